// Round 2
// baseline (2843.160 us; speedup 1.0000x reference)
//
#include <hip/hip_runtime.h>
#include <hip/hip_bf16.h>

#define NN 2048
#define SEQL 64
#define DIM 256
#define NHEAD 8
#define EDGES 32768
#define CHUNKS 4
#define CN (NN / CHUNKS)          // 512 nodes per chunk
#define CROWS (CN * SEQL)         // 32768 rows per chunk

typedef __attribute__((ext_vector_type(8))) short short8;
typedef __attribute__((ext_vector_type(4))) float f32x4;
typedef __attribute__((ext_vector_type(4))) unsigned short us4;
typedef unsigned short ushort_t;

__device__ __forceinline__ float us2f(unsigned short u) {
    union { unsigned int i; float f; } x; x.i = ((unsigned int)u) << 16; return x.f;
}
__device__ __forceinline__ unsigned short f2us(float f) {
    union { float f; unsigned int i; } u; u.f = f;
    unsigned int r = u.i + 0x7fffu + ((u.i >> 16) & 1u);
    return (unsigned short)(r >> 16);
}
__device__ __forceinline__ float lrelu02(float v) { return v < 0.f ? 0.2f * v : v; }

// ---------------------------------------------------------------------------
// Input dtype sniffing + canonicalization to bf16.
// bf16-packed u32: bits[14:7] = exponent of low element (clustered ~0x73-0x7C
// for N(0,0.02) data). f32 u32: bits[14:7] = mantissa bits (uniform).
// ---------------------------------------------------------------------------
__global__ void sniff_kernel(const unsigned int* __restrict__ w, int* __restrict__ flag) {
    __shared__ int cnt;
    if (threadIdx.x == 0) cnt = 0;
    __syncthreads();
    unsigned int v = w[(size_t)threadIdx.x * 509];   // max 255*509=129795 < 196608 words
    unsigned int e_lo = (v >> 7) & 0xffu;
    if (e_lo >= 0x6eu && e_lo <= 0x7fu) atomicAdd(&cnt, 1);
    __syncthreads();
    if (threadIdx.x == 0) *flag = (cnt > 128) ? 1 : 0;   // 1 = inputs are bf16
}

struct ConvArgs {
    const void* src[24];
    unsigned int off[25];   // padded prefix (elements)
    unsigned int sz[24];    // true element counts
};

__global__ void convert_kernel(ConvArgs a, const int* __restrict__ flag,
                               ushort_t* __restrict__ dst, unsigned int total) {
    const int bf = *flag;
    for (unsigned int i = blockIdx.x * 256 + threadIdx.x; i < total; i += gridDim.x * 256) {
        int s = 0;
        while (a.off[s + 1] <= i) ++s;
        unsigned int j = i - a.off[s];
        ushort_t v = 0;
        if (j < a.sz[s]) {
            if (bf) v = ((const ushort_t*)a.src[s])[j];
            else    v = f2us(((const float*)a.src[s])[j]);
        }
        dst[i] = v;
    }
}

// ---------------------------------------------------------------------------
// Generic bf16 MFMA GEMM: C[M,N] = A[M,K] @ B[K,N] (+bias) (+relu)
// A,B bf16 row-major. M%128==0, N%128==0, K%32==0 (all shapes here comply).
// ---------------------------------------------------------------------------
template <bool RELU, bool OUT_BF16>
__global__ __launch_bounds__(256) void gemm_kernel(
    const ushort_t* __restrict__ A, const ushort_t* __restrict__ B,
    const ushort_t* __restrict__ bias, void* __restrict__ C,
    int M, int N, int K)
{
    __shared__ __align__(16) short a_lds[128][40];   // [row][k]
    __shared__ __align__(16) short b_lds[128][40];   // [col][k] (B transposed)

    const int tid  = threadIdx.x;
    const int lane = tid & 63;
    const int wave = tid >> 6;
    const int wr = wave >> 1, wc = wave & 1;
    const size_t mbase = (size_t)blockIdx.x * 128;
    const size_t nbase = (size_t)blockIdx.y * 128;

    f32x4 acc[4][4];
    const f32x4 fzero = {0.f, 0.f, 0.f, 0.f};
#pragma unroll
    for (int i = 0; i < 4; ++i)
#pragma unroll
        for (int j = 0; j < 4; ++j) acc[i][j] = fzero;

    const int ar = tid >> 2;            // 0..63 (A row within half-tile)
    const int ac = (tid & 3) * 8;       // k offset 0/8/16/24
    const int bk = tid >> 4;            // 0..15 (B k-row within half)
    const int bc = (tid & 15) * 8;      // col offset 0..120

    const int rl = lane & 15;
    const int kf = (lane >> 4) * 8;

    for (int k0 = 0; k0 < K; k0 += 32) {
        __syncthreads();
#pragma unroll
        for (int p = 0; p < 2; ++p) {
            int r = ar + p * 64;
            short8 v = *(const short8*)(A + (mbase + r) * (size_t)K + k0 + ac);
            *(short8*)&a_lds[r][ac] = v;
        }
#pragma unroll
        for (int p = 0; p < 2; ++p) {
            int kk = bk + p * 16;
            union { short8 v; short s[8]; } u;
            u.v = *(const short8*)(B + (size_t)(k0 + kk) * N + nbase + bc);
#pragma unroll
            for (int j = 0; j < 8; ++j) b_lds[bc + j][kk] = u.s[j];
        }
        __syncthreads();

        short8 af[4], bfr[4];
#pragma unroll
        for (int m = 0; m < 4; ++m) af[m] = *(const short8*)&a_lds[wr * 64 + m * 16 + rl][kf];
#pragma unroll
        for (int n = 0; n < 4; ++n) bfr[n] = *(const short8*)&b_lds[wc * 64 + n * 16 + rl][kf];
#pragma unroll
        for (int m = 0; m < 4; ++m)
#pragma unroll
            for (int n = 0; n < 4; ++n)
                acc[m][n] = __builtin_amdgcn_mfma_f32_16x16x32_bf16(af[m], bfr[n], acc[m][n], 0, 0, 0);
    }

    const int rq = (lane >> 4) * 4;
#pragma unroll
    for (int m = 0; m < 4; ++m) {
#pragma unroll
        for (int n = 0; n < 4; ++n) {
            size_t gcol = nbase + wc * 64 + n * 16 + rl;
            float bv = bias ? us2f(bias[gcol]) : 0.f;
#pragma unroll
            for (int q = 0; q < 4; ++q) {
                size_t grow = mbase + wr * 64 + m * 16 + rq + q;
                float v = acc[m][n][q] + bv;
                if (RELU) v = fmaxf(v, 0.f);
                if (OUT_BF16) ((ushort_t*)C)[grow * N + gcol] = f2us(v);
                else          ((float*)C)[grow * N + gcol] = v;
            }
        }
    }
}

// ---------------------------------------------------------------------------
// Positional encoding table [64][256] f32
// ---------------------------------------------------------------------------
__global__ void pe_kernel(float* __restrict__ pe) {
    int s = blockIdx.x, d = threadIdx.x;
    int i = d >> 1;
    float freq = __expf((float)(2 * i) * (-9.210340371976184f / 256.f));
    float ang = (float)s * freq;
    pe[s * DIM + d] = (d & 1) ? cosf(ang) : sinf(ang);
}

// x = tok_emb[tok]*16 + pe[s]; tok_emb dtype resolved at runtime via flag
__global__ void embed_kernel(const void* __restrict__ tok_emb,
                             const int* __restrict__ flag,
                             const int* __restrict__ tokens,
                             const float* __restrict__ pe,
                             ushort_t* __restrict__ X, int row0) {
    int lr = blockIdx.x, d = threadIdx.x;
    int grow = row0 + lr;
    int tok = tokens[grow];
    int s = grow & 63;
    size_t idx = (size_t)tok * DIM + d;
    float tv = (*flag) ? us2f(((const ushort_t*)tok_emb)[idx])
                       : ((const float*)tok_emb)[idx];
    float v = tv * 16.f + pe[s * DIM + d];
    X[(size_t)lr * DIM + d] = f2us(v);
}

// ---------------------------------------------------------------------------
// Attention: 1 wave per (node, head). K/V staged to LDS as f32.
// ---------------------------------------------------------------------------
__global__ __launch_bounds__(64) void attn_kernel(const ushort_t* __restrict__ qkv,
                                                  ushort_t* __restrict__ O) {
    __shared__ __align__(16) float k_lds[64][36];
    __shared__ __align__(16) float v_lds[64][36];
    const int nl = blockIdx.x, h = blockIdx.y, lane = threadIdx.x;
    const size_t rowbase = (size_t)nl * 64;

    const ushort_t* kp = qkv + (rowbase + lane) * 768 + 256 + h * 32;
    const ushort_t* vp = kp + 256;
#pragma unroll
    for (int c = 0; c < 4; ++c) {
        union { short8 v; unsigned short s[8]; } uk, uv;
        uk.v = *(const short8*)(kp + c * 8);
        uv.v = *(const short8*)(vp + c * 8);
#pragma unroll
        for (int j = 0; j < 8; ++j) {
            k_lds[lane][c * 8 + j] = us2f(uk.s[j]);
            v_lds[lane][c * 8 + j] = us2f(uv.s[j]);
        }
    }
    float qf[32];
    const ushort_t* qp = qkv + (rowbase + lane) * 768 + h * 32;
#pragma unroll
    for (int c = 0; c < 4; ++c) {
        union { short8 v; unsigned short s[8]; } uq;
        uq.v = *(const short8*)(qp + c * 8);
#pragma unroll
        for (int j = 0; j < 8; ++j) qf[c * 8 + j] = us2f(uq.s[j]);
    }
    __syncthreads();

    float s[64];
#pragma unroll
    for (int j = 0; j < 64; ++j) {
        float acc = 0.f;
#pragma unroll
        for (int c = 0; c < 8; ++c) {
            f32x4 kv = *(const f32x4*)&k_lds[j][c * 4];
            acc += qf[c * 4 + 0] * kv[0] + qf[c * 4 + 1] * kv[1] +
                   qf[c * 4 + 2] * kv[2] + qf[c * 4 + 3] * kv[3];
        }
        s[j] = acc * 0.17677669529663687f;
    }
    float mx = -1e30f;
#pragma unroll
    for (int j = 0; j < 64; ++j) mx = fmaxf(mx, s[j]);
    float sum = 0.f;
#pragma unroll
    for (int j = 0; j < 64; ++j) { s[j] = __expf(s[j] - mx); sum += s[j]; }
    float inv = 1.f / sum;

    float o[32];
#pragma unroll
    for (int d = 0; d < 32; ++d) o[d] = 0.f;
#pragma unroll
    for (int j = 0; j < 64; ++j) {
        float pw = s[j];
#pragma unroll
        for (int c = 0; c < 8; ++c) {
            f32x4 vv = *(const f32x4*)&v_lds[j][c * 4];
            o[c * 4 + 0] += pw * vv[0]; o[c * 4 + 1] += pw * vv[1];
            o[c * 4 + 2] += pw * vv[2]; o[c * 4 + 3] += pw * vv[3];
        }
    }
    ushort_t* op = O + (rowbase + lane) * DIM + h * 32;
#pragma unroll
    for (int c = 0; c < 8; ++c) {
        us4 w;
#pragma unroll
        for (int j = 0; j < 4; ++j) w[j] = f2us(o[c * 4 + j] * inv);
        *(us4*)(op + c * 4) = w;
    }
}

// X = LN(X + T) * g + b, one wave per row of 256
__global__ __launch_bounds__(64) void add_ln_kernel(ushort_t* __restrict__ X,
                                                    const float* __restrict__ T,
                                                    const ushort_t* __restrict__ g,
                                                    const ushort_t* __restrict__ b) {
    const size_t row = blockIdx.x;
    const int lane = threadIdx.x, d0 = lane * 4;
    us4 xv = *(const us4*)&X[row * DIM + d0];
    f32x4 tv = *(const f32x4*)&T[row * DIM + d0];
    float v[4];
    float sum = 0.f, sq = 0.f;
#pragma unroll
    for (int j = 0; j < 4; ++j) { v[j] = us2f(xv[j]) + tv[j]; sum += v[j]; sq += v[j] * v[j]; }
#pragma unroll
    for (int off = 32; off > 0; off >>= 1) { sum += __shfl_xor(sum, off); sq += __shfl_xor(sq, off); }
    float mean = sum * (1.f / 256.f);
    float var = sq * (1.f / 256.f) - mean * mean;
    float inv = rsqrtf(var + 1e-5f);
    us4 out;
#pragma unroll
    for (int j = 0; j < 4; ++j)
        out[j] = f2us((v[j] - mean) * inv * us2f(g[d0 + j]) + us2f(b[d0 + j]));
    *(us4*)&X[row * DIM + d0] = out;
}

// h[n] = mean_s X[n,s,:] + type_emb[type[n]]
__global__ void mean_kernel(const ushort_t* __restrict__ Xc,
                            const ushort_t* __restrict__ type_emb,
                            const int* __restrict__ rtypes,
                            float* __restrict__ h, ushort_t* __restrict__ hb, int n0) {
    int nl = blockIdx.x, d = threadIdx.x;
    float acc = 0.f;
    for (int s = 0; s < 64; ++s) acc += us2f(Xc[((size_t)nl * 64 + s) * DIM + d]);
    int n = n0 + nl;
    float val = acc * (1.f / 64.f) + us2f(type_emb[(size_t)rtypes[n] * DIM + d]);
    h[(size_t)n * DIM + d] = val;
    hb[(size_t)n * DIM + d] = f2us(val);
}

// ---------------------------------------------------------------------------
// CSR build (by dst)
// ---------------------------------------------------------------------------
__global__ void hist_kernel(const int* __restrict__ ei, int* __restrict__ counts) {
    int e = blockIdx.x * 256 + threadIdx.x;
    if (e < EDGES) atomicAdd(&counts[ei[EDGES + e]], 1);
}
__global__ __launch_bounds__(256) void scan_kernel(const int* __restrict__ counts,
                                                   int* __restrict__ indptr,
                                                   int* __restrict__ cursor) {
    __shared__ int part[256];
    int t = threadIdx.x;
    int local[8]; int s = 0;
#pragma unroll
    for (int i = 0; i < 8; ++i) { local[i] = s; s += counts[t * 8 + i]; }
    part[t] = s;
    __syncthreads();
    for (int d = 1; d < 256; d <<= 1) {
        int val = (t >= d) ? part[t - d] : 0;
        __syncthreads();
        part[t] += val;
        __syncthreads();
    }
    int base = part[t] - s;
#pragma unroll
    for (int i = 0; i < 8; ++i) { int v = base + local[i]; indptr[t * 8 + i] = v; cursor[t * 8 + i] = v; }
    if (t == 255) indptr[NN] = part[255];
}
__global__ void scatter_kernel(const int* __restrict__ ei, const int* __restrict__ et,
                               int* __restrict__ cursor, int* __restrict__ col_src,
                               int* __restrict__ col_type) {
    int e = blockIdx.x * 256 + threadIdx.x;
    if (e < EDGES) {
        int d = ei[EDGES + e];
        int pp = atomicAdd(&cursor[d], 1);
        col_src[pp] = ei[e];
        col_type[pp] = et[e];
    }
}

// a_s/a_d dot products: block per node, wave per GAT head
__global__ __launch_bounds__(256) void asad_kernel(const float* __restrict__ xg,
                                                   const ushort_t* __restrict__ asrc,
                                                   const ushort_t* __restrict__ adst,
                                                   float* __restrict__ a_s, float* __restrict__ a_d,
                                                   int l) {
    int n = blockIdx.x, g = threadIdx.x >> 6, lane = threadIdx.x & 63;
    const float* xp = xg + (size_t)n * 1024 + g * 256 + lane * 4;
    const ushort_t* sp = asrc + ((size_t)l * 4 + g) * 256 + lane * 4;
    const ushort_t* dp = adst + ((size_t)l * 4 + g) * 256 + lane * 4;
    float ss = 0.f, dd = 0.f;
#pragma unroll
    for (int j = 0; j < 4; ++j) { float x = xp[j]; ss += x * us2f(sp[j]); dd += x * us2f(dp[j]); }
#pragma unroll
    for (int off = 32; off > 0; off >>= 1) { ss += __shfl_xor(ss, off); dd += __shfl_xor(dd, off); }
    if (lane == 0) { a_s[n * 4 + g] = ss; a_d[n * 4 + g] = dd; }
}

// GAT edge-softmax + aggregate: block per dst node, wave per head
__global__ __launch_bounds__(256) void edge_kernel(const float* __restrict__ xg,
                                                   const float* __restrict__ a_s,
                                                   const float* __restrict__ a_d,
                                                   const int* __restrict__ indptr,
                                                   const int* __restrict__ col_src,
                                                   const int* __restrict__ col_type,
                                                   const ushort_t* __restrict__ gat_b,
                                                   float* __restrict__ h_new, int l, int r) {
    __shared__ float outs[4][256];
    int n = blockIdx.x, g = threadIdx.x >> 6, lane = threadIdx.x & 63;
    int beg = indptr[n], end = indptr[n + 1];
    float adn = a_d[n * 4 + g];
    float eself = lrelu02(a_s[n * 4 + g] + adn);
    float m = eself;
    for (int e = beg; e < end; ++e) {
        if (col_type[e] == r) {
            float v = lrelu02(a_s[col_src[e] * 4 + g] + adn);
            m = fmaxf(m, v);
        }
    }
    float wself = __expf(eself - m);
    float denom = wself;
    const float* xn = xg + (size_t)n * 1024 + g * 256 + lane * 4;
    float num[4];
#pragma unroll
    for (int j = 0; j < 4; ++j) num[j] = wself * xn[j];
    for (int e = beg; e < end; ++e) {
        if (col_type[e] == r) {
            int src = col_src[e];
            float v = lrelu02(a_s[src * 4 + g] + adn);
            float w = __expf(v - m);
            denom += w;
            const float* xs = xg + (size_t)src * 1024 + g * 256 + lane * 4;
#pragma unroll
            for (int j = 0; j < 4; ++j) num[j] += w * xs[j];
        }
    }
    float invd = 1.f / denom;
#pragma unroll
    for (int j = 0; j < 4; ++j) outs[g][lane * 4 + j] = num[j] * invd;
    __syncthreads();
    int d = threadIdx.x;
    float hv = 0.25f * (outs[0][d] + outs[1][d] + outs[2][d] + outs[3][d]) + us2f(gat_b[l * 256 + d]);
    h_new[(size_t)n * 256 + d] += hv;
}

__global__ void update_h_kernel(float* __restrict__ h, const float* __restrict__ h_new,
                                ushort_t* __restrict__ hb) {
    size_t i = (size_t)blockIdx.x * 256 + threadIdx.x;
    float v = fmaxf(h[i] + h_new[i], 0.f);
    h[i] = v;
    hb[i] = f2us(v);
}

// Lorentz exp-map head: block (wave) per node; out dtype via flag
__global__ __launch_bounds__(64) void final_kernel(const float* __restrict__ pos,
                                                   const ushort_t* __restrict__ log_c,
                                                   const int* __restrict__ flag,
                                                   void* __restrict__ out) {
    int n = blockIdx.x, lane = threadIdx.x;
    int bf = *flag;
    float sc = sqrtf(__expf(us2f(log_c[0])));
    f32x4 pv = *(const f32x4*)&pos[(size_t)n * 256 + lane * 4];
    float st[4]; float sq = 0.f;
#pragma unroll
    for (int j = 0; j < 4; ++j) { float t = tanhf(pv[j]) * 2.f * sc; st[j] = t; sq += t * t; }
#pragma unroll
    for (int off = 32; off > 0; off >>= 1) sq += __shfl_xor(sq, off);
    float rr = fmaxf(sqrtf(sq), 1e-8f);
    float sf = sinhf(rr) / rr;
    if (bf) {
        ushort_t* o = (ushort_t*)out;
        if (lane == 0) o[(size_t)n * 257] = f2us(coshf(rr));
#pragma unroll
        for (int j = 0; j < 4; ++j) o[(size_t)n * 257 + 1 + lane * 4 + j] = f2us(sf * st[j]);
    } else {
        float* o = (float*)out;
        if (lane == 0) o[(size_t)n * 257] = coshf(rr);
#pragma unroll
        for (int j = 0; j < 4; ++j) o[(size_t)n * 257 + 1 + lane * 4 + j] = sf * st[j];
    }
}

// ---------------------------------------------------------------------------
extern "C" void kernel_launch(void* const* d_in, const int* in_sizes, int n_in,
                              void* d_out, int out_size, void* d_ws, size_t ws_size,
                              hipStream_t stream) {
    const int* tokens = (const int*)d_in[25];
    const int* rtypes = (const int*)d_in[26];
    const int* eidx   = (const int*)d_in[27];
    const int* etype  = (const int*)d_in[28];

    char* p = (char*)d_ws;
    auto alloc = [&](size_t b) -> char* { char* r = p; p += (b + 255) & ~(size_t)255; return r; };

    int*      flag   = (int*)     alloc(256);
    // canonical bf16 weights (inputs 1..24), padded offsets
    ConvArgs ca;
    unsigned int woff[25];
    {
        unsigned int off = 0;
        for (int k = 0; k < 24; ++k) {
            ca.src[k] = d_in[k + 1];
            ca.off[k] = off;
            ca.sz[k]  = (unsigned int)in_sizes[k + 1];
            woff[k] = off;
            off += (unsigned int)((in_sizes[k + 1] + 7) & ~7);
        }
        ca.off[24] = off;
        woff[24] = off;
    }
    ushort_t* wtb    = (ushort_t*)alloc((size_t)woff[24] * 2);
    float*    pe     = (float*)   alloc((size_t)SEQL * DIM * 4);
    ushort_t* Xc     = (ushort_t*)alloc((size_t)CROWS * DIM * 2);
    ushort_t* QKV    = (ushort_t*)alloc((size_t)CROWS * 768 * 2);
    ushort_t* Oc     = (ushort_t*)alloc((size_t)CROWS * DIM * 2);
    float*    tmp    = (float*)   alloc((size_t)CROWS * DIM * 4);
    float*    h      = (float*)   alloc((size_t)NN * DIM * 4);
    ushort_t* hb     = (ushort_t*)alloc((size_t)NN * DIM * 2);
    float*    hnew   = (float*)   alloc((size_t)NN * DIM * 4);
    ushort_t* th     = (ushort_t*)alloc((size_t)NN * DIM * 2);
    float*    xg     = (float*)   alloc((size_t)NN * 1024 * 4);
    float*    a_s    = (float*)   alloc((size_t)NN * 4 * 4);
    float*    a_d    = (float*)   alloc((size_t)NN * 4 * 4);
    ushort_t* thead  = (ushort_t*)alloc((size_t)NN * 512 * 2);
    float*    posb   = (float*)   alloc((size_t)NN * DIM * 4);
    int*      counts = (int*)     alloc((size_t)NN * 4);
    int*      indptr = (int*)     alloc((size_t)(NN + 1) * 4);
    int*      cursor = (int*)     alloc((size_t)NN * 4);
    int*      col_src  = (int*)   alloc((size_t)EDGES * 4);
    int*      col_type = (int*)   alloc((size_t)EDGES * 4);

    // weight pointers into canonical bf16 region (input idx k -> woff[k-1])
    const ushort_t* Wqkv = wtb + woff[0];
    const ushort_t* bqkv = wtb + woff[1];
    const ushort_t* Wo   = wtb + woff[2];
    const ushort_t* bo   = wtb + woff[3];
    const ushort_t* ln1g = wtb + woff[4];
    const ushort_t* ln1b = wtb + woff[5];
    const ushort_t* ln2g = wtb + woff[6];
    const ushort_t* ln2b = wtb + woff[7];
    const ushort_t* W1   = wtb + woff[8];
    const ushort_t* b1   = wtb + woff[9];
    const ushort_t* W2   = wtb + woff[10];
    const ushort_t* b2   = wtb + woff[11];
    const ushort_t* type_emb = wtb + woff[12];
    const ushort_t* msg_W = wtb + woff[13];
    const ushort_t* msg_b = wtb + woff[14];
    const ushort_t* gat_W = wtb + woff[15];
    const ushort_t* gat_b = wtb + woff[16];
    const ushort_t* gasrc = wtb + woff[17];
    const ushort_t* gadst = wtb + woff[18];
    const ushort_t* spW1 = wtb + woff[19];
    const ushort_t* spb1 = wtb + woff[20];
    const ushort_t* spW2 = wtb + woff[21];
    const ushort_t* spb2 = wtb + woff[22];
    const ushort_t* log_c = wtb + woff[23];

    sniff_kernel<<<1, 256, 0, stream>>>((const unsigned int*)d_in[1], flag);
    convert_kernel<<<2048, 256, 0, stream>>>(ca, flag, wtb, woff[24]);

    pe_kernel<<<SEQL, DIM, 0, stream>>>(pe);
    hipMemsetAsync(counts, 0, NN * 4, stream);
    hist_kernel<<<EDGES / 256, 256, 0, stream>>>(eidx, counts);
    scan_kernel<<<1, 256, 0, stream>>>(counts, indptr, cursor);
    scatter_kernel<<<EDGES / 256, 256, 0, stream>>>(eidx, etype, cursor, col_src, col_type);

    for (int c = 0; c < CHUNKS; ++c) {
        int row0 = c * CROWS;
        embed_kernel<<<CROWS, DIM, 0, stream>>>(d_in[0], flag, tokens, pe, Xc, row0);
        for (int l = 0; l < 2; ++l) {
            gemm_kernel<false, true><<<dim3(CROWS / 128, 6), 256, 0, stream>>>(
                Xc, Wqkv + (size_t)l * DIM * 768, bqkv + l * 768, QKV, CROWS, 768, DIM);
            attn_kernel<<<dim3(CN, NHEAD), 64, 0, stream>>>(QKV, Oc);
            gemm_kernel<false, false><<<dim3(CROWS / 128, 2), 256, 0, stream>>>(
                Oc, Wo + (size_t)l * DIM * DIM, bo + l * DIM, tmp, CROWS, DIM, DIM);
            add_ln_kernel<<<CROWS, 64, 0, stream>>>(Xc, tmp, ln1g + l * DIM, ln1b + l * DIM);
            gemm_kernel<true, true><<<dim3(CROWS / 128, 2), 256, 0, stream>>>(
                Xc, W1 + (size_t)l * DIM * DIM, b1 + l * DIM, Oc, CROWS, DIM, DIM);
            gemm_kernel<false, false><<<dim3(CROWS / 128, 2), 256, 0, stream>>>(
                Oc, W2 + (size_t)l * DIM * DIM, b2 + l * DIM, tmp, CROWS, DIM, DIM);
            add_ln_kernel<<<CROWS, 64, 0, stream>>>(Xc, tmp, ln2g + l * DIM, ln2b + l * DIM);
        }
        mean_kernel<<<CN, DIM, 0, stream>>>(Xc, type_emb, rtypes, h, hb, c * CN);
    }

    for (int l = 0; l < 4; ++l) {
        hipMemsetAsync(hnew, 0, (size_t)NN * DIM * 4, stream);
        for (int r = 0; r < 3; ++r) {
            gemm_kernel<false, true><<<dim3(NN / 128, 2), 256, 0, stream>>>(
                hb, msg_W + (size_t)r * DIM * DIM, msg_b + r * DIM, th, NN, DIM, DIM);
            gemm_kernel<false, false><<<dim3(NN / 128, 8), 256, 0, stream>>>(
                th, gat_W + (size_t)l * DIM * 1024, nullptr, xg, NN, 1024, DIM);
            asad_kernel<<<NN, 256, 0, stream>>>(xg, gasrc, gadst, a_s, a_d, l);
            edge_kernel<<<NN, 256, 0, stream>>>(xg, a_s, a_d, indptr, col_src, col_type,
                                                gat_b, hnew, l, r);
        }
        update_h_kernel<<<NN, 256, 0, stream>>>(h, hnew, hb);
    }

    gemm_kernel<true, true><<<dim3(NN / 128, 4), 256, 0, stream>>>(hb, spW1, spb1, thead, NN, 512, DIM);
    gemm_kernel<false, false><<<dim3(NN / 128, 2), 256, 0, stream>>>(thead, spW2, spb2, posb, NN, DIM, 512);
    final_kernel<<<NN, 64, 0, stream>>>(posb, log_c, flag, d_out);
}

// Round 3
// 1586.454 us; speedup vs baseline: 1.7921x; 1.7921x over previous
//
#include <hip/hip_runtime.h>
#include <hip/hip_bf16.h>

#define NN 2048
#define SEQL 64
#define DIM 256
#define NHEAD 8
#define EDGES 32768
#define CHUNKS 4
#define CN (NN / CHUNKS)          // 512 nodes per chunk
#define CROWS (CN * SEQL)         // 32768 rows per chunk

typedef __attribute__((ext_vector_type(8))) short short8;
typedef __attribute__((ext_vector_type(4))) float f32x4;
typedef __attribute__((ext_vector_type(4))) unsigned short us4;
typedef unsigned short ushort_t;

__device__ __forceinline__ float us2f(unsigned short u) {
    union { unsigned int i; float f; } x; x.i = ((unsigned int)u) << 16; return x.f;
}
__device__ __forceinline__ unsigned short f2us(float f) {
    union { float f; unsigned int i; } u; u.f = f;
    unsigned int r = u.i + 0x7fffu + ((u.i >> 16) & 1u);
    return (unsigned short)(r >> 16);
}
__device__ __forceinline__ float lrelu02(float v) { return v < 0.f ? 0.2f * v : v; }

// ---------------------------------------------------------------------------
// dtype sniff (bf16-packed vs f32 inputs)
// ---------------------------------------------------------------------------
__global__ void sniff_kernel(const unsigned int* __restrict__ w, int* __restrict__ flag) {
    __shared__ int cnt;
    if (threadIdx.x == 0) cnt = 0;
    __syncthreads();
    unsigned int v = w[(size_t)threadIdx.x * 509];
    unsigned int e_lo = (v >> 7) & 0xffu;
    if (e_lo >= 0x6eu && e_lo <= 0x7fu) atomicAdd(&cnt, 1);
    __syncthreads();
    if (threadIdx.x == 0) *flag = (cnt > 128) ? 1 : 0;   // 1 = inputs are bf16
}

// ---------------------------------------------------------------------------
// Weight canonicalization to bf16, with optional per-slice transpose
// dst tensor layout [N][K] from src [K][N]  (K power of two)
// ---------------------------------------------------------------------------
#define NE 33
struct ConvArgs {
    const void* src[NE];
    unsigned int soff[NE];      // element offset into src (slice base)
    unsigned int off[NE + 1];   // padded dst offsets (elements)
    unsigned int nel[NE];       // true element count
    unsigned short ncol[NE];    // N (src cols) when transposing
    unsigned char klog2[NE];    // log2(K) when transposing, 0 = plain copy
};

__global__ void convert_kernel(ConvArgs a, const int* __restrict__ flag,
                               ushort_t* __restrict__ dst, unsigned int total) {
    const int bf = *flag;
    for (unsigned int i = blockIdx.x * 256 + threadIdx.x; i < total; i += gridDim.x * 256) {
        int e = 0;
        while (a.off[e + 1] <= i) ++e;
        unsigned int j = i - a.off[e];
        ushort_t v = 0;
        if (j < a.nel[e]) {
            unsigned int sidx;
            if (a.klog2[e]) {
                unsigned int K = 1u << a.klog2[e];
                unsigned int k = j & (K - 1), n = j >> a.klog2[e];
                sidx = k * (unsigned int)a.ncol[e] + n;
            } else sidx = j;
            sidx += a.soff[e];
            if (bf) v = ((const ushort_t*)a.src[e])[sidx];
            else    v = f2us(((const float*)a.src[e])[sidx]);
        }
        dst[i] = v;
    }
}

// ---------------------------------------------------------------------------
// bf16 MFMA GEMM with pre-transposed B: C[M,N] = A[M,K] @ B^T[N,K]^T
// ---------------------------------------------------------------------------
template <bool RELU, bool OUT_BF16>
__global__ __launch_bounds__(256) void gemm_bt(
    const ushort_t* __restrict__ A, const ushort_t* __restrict__ BT,
    const ushort_t* __restrict__ bias, void* __restrict__ C,
    int M, int N, int K)
{
    __shared__ __align__(16) short a_lds[128][40];
    __shared__ __align__(16) short b_lds[128][40];

    const int tid  = threadIdx.x;
    const int lane = tid & 63;
    const int wave = tid >> 6;
    const int wr = wave >> 1, wc = wave & 1;
    const size_t mbase = (size_t)blockIdx.x * 128;
    const size_t nbase = (size_t)blockIdx.y * 128;

    f32x4 acc[4][4];
    const f32x4 fzero = {0.f, 0.f, 0.f, 0.f};
#pragma unroll
    for (int i = 0; i < 4; ++i)
#pragma unroll
        for (int j = 0; j < 4; ++j) acc[i][j] = fzero;

    const int ar = tid >> 2;            // 0..63
    const int ac = (tid & 3) * 8;       // k offset
    const int rl = lane & 15;
    const int kf = (lane >> 4) * 8;

    for (int k0 = 0; k0 < K; k0 += 32) {
        __syncthreads();
#pragma unroll
        for (int p = 0; p < 2; ++p) {
            int r = ar + p * 64;
            *(short8*)&a_lds[r][ac] = *(const short8*)(A  + (mbase + r) * (size_t)K + k0 + ac);
            *(short8*)&b_lds[r][ac] = *(const short8*)(BT + (nbase + r) * (size_t)K + k0 + ac);
        }
        __syncthreads();

        short8 af[4], bfr[4];
#pragma unroll
        for (int m = 0; m < 4; ++m) af[m]  = *(const short8*)&a_lds[wr * 64 + m * 16 + rl][kf];
#pragma unroll
        for (int n = 0; n < 4; ++n) bfr[n] = *(const short8*)&b_lds[wc * 64 + n * 16 + rl][kf];
#pragma unroll
        for (int m = 0; m < 4; ++m)
#pragma unroll
            for (int n = 0; n < 4; ++n)
                acc[m][n] = __builtin_amdgcn_mfma_f32_16x16x32_bf16(af[m], bfr[n], acc[m][n], 0, 0, 0);
    }

    const int rq = (lane >> 4) * 4;
#pragma unroll
    for (int m = 0; m < 4; ++m) {
#pragma unroll
        for (int n = 0; n < 4; ++n) {
            size_t gcol = nbase + wc * 64 + n * 16 + rl;
            float bv = bias ? us2f(bias[gcol]) : 0.f;
#pragma unroll
            for (int q = 0; q < 4; ++q) {
                size_t grow = mbase + wr * 64 + m * 16 + rq + q;
                float v = acc[m][n][q] + bv;
                if (RELU) v = fmaxf(v, 0.f);
                if (OUT_BF16) ((ushort_t*)C)[grow * N + gcol] = f2us(v);
                else          ((float*)C)[grow * N + gcol] = v;
            }
        }
    }
}

// ---------------------------------------------------------------------------
// Fused GEMM + residual + LayerNorm (N=256 fixed):
// X = LN(X + A @ BT^T + bias) * g + b   (in-place on X, bf16)
// tile 128 rows x 256 cols, 512 threads (8 waves, 2x4)
// ---------------------------------------------------------------------------
__global__ __launch_bounds__(512) void gemm_ln(
    const ushort_t* __restrict__ A, const ushort_t* __restrict__ BT,
    const ushort_t* __restrict__ bias, ushort_t* __restrict__ X,
    const ushort_t* __restrict__ gg, const ushort_t* __restrict__ bb, int K)
{
    __shared__ __align__(16) short a_lds[128][40];
    __shared__ __align__(16) short b_lds[256][40];
    __shared__ float st_part[128][8];   // [row][wc]=sum, [row][4+wc]=sq
    __shared__ float st_fin[128][2];    // mean, inv

    const int tid  = threadIdx.x;
    const int lane = tid & 63;
    const int wave = tid >> 6;
    const int wr = wave >> 2, wc = wave & 3;
    const size_t mbase = (size_t)blockIdx.x * 128;

    f32x4 acc[4][4];
    const f32x4 fzero = {0.f, 0.f, 0.f, 0.f};
#pragma unroll
    for (int i = 0; i < 4; ++i)
#pragma unroll
        for (int j = 0; j < 4; ++j) acc[i][j] = fzero;

    const int ar = tid >> 2;            // 0..127
    const int ac = (tid & 3) * 8;
    const int br = tid >> 1;            // 0..255
    const int bc0 = (tid & 1) * 16;
    const int rl = lane & 15;
    const int g  = lane >> 4;
    const int kf = g * 8;

    for (int k0 = 0; k0 < K; k0 += 32) {
        __syncthreads();
        *(short8*)&a_lds[ar][ac] = *(const short8*)(A + (mbase + ar) * (size_t)K + k0 + ac);
        *(short8*)&b_lds[br][bc0]     = *(const short8*)(BT + (size_t)br * K + k0 + bc0);
        *(short8*)&b_lds[br][bc0 + 8] = *(const short8*)(BT + (size_t)br * K + k0 + bc0 + 8);
        __syncthreads();

        short8 af[4], bfr[4];
#pragma unroll
        for (int m = 0; m < 4; ++m) af[m]  = *(const short8*)&a_lds[wr * 64 + m * 16 + rl][kf];
#pragma unroll
        for (int n = 0; n < 4; ++n) bfr[n] = *(const short8*)&b_lds[wc * 64 + n * 16 + rl][kf];
#pragma unroll
        for (int m = 0; m < 4; ++m)
#pragma unroll
            for (int n = 0; n < 4; ++n)
                acc[m][n] = __builtin_amdgcn_mfma_f32_16x16x32_bf16(af[m], bfr[n], acc[m][n], 0, 0, 0);
    }

    // v = acc + bias + residual
#pragma unroll
    for (int m = 0; m < 4; ++m)
#pragma unroll
        for (int n = 0; n < 4; ++n) {
            int gcol = wc * 64 + n * 16 + rl;
            float bv = us2f(bias[gcol]);
#pragma unroll
            for (int r = 0; r < 4; ++r) {
                size_t grow = mbase + wr * 64 + m * 16 + g * 4 + r;
                acc[m][n][r] += bv + us2f(X[grow * 256 + gcol]);
            }
        }
    // per-row partial sums over this wave's 64 cols
#pragma unroll
    for (int m = 0; m < 4; ++m)
#pragma unroll
        for (int r = 0; r < 4; ++r) {
            float ps = 0.f, pq = 0.f;
#pragma unroll
            for (int n = 0; n < 4; ++n) { float v = acc[m][n][r]; ps += v; pq += v * v; }
#pragma unroll
            for (int off = 1; off < 16; off <<= 1) { ps += __shfl_xor(ps, off); pq += __shfl_xor(pq, off); }
            if (rl == 0) {
                int row = wr * 64 + m * 16 + g * 4 + r;
                st_part[row][wc] = ps;
                st_part[row][4 + wc] = pq;
            }
        }
    __syncthreads();
    if (tid < 128) {
        float s = st_part[tid][0] + st_part[tid][1] + st_part[tid][2] + st_part[tid][3];
        float q = st_part[tid][4] + st_part[tid][5] + st_part[tid][6] + st_part[tid][7];
        float mean = s * (1.f / 256.f);
        float var = q * (1.f / 256.f) - mean * mean;
        st_fin[tid][0] = mean;
        st_fin[tid][1] = rsqrtf(var + 1e-5f);
    }
    __syncthreads();
#pragma unroll
    for (int m = 0; m < 4; ++m)
#pragma unroll
        for (int n = 0; n < 4; ++n) {
            int gcol = wc * 64 + n * 16 + rl;
            float gv = us2f(gg[gcol]), bv = us2f(bb[gcol]);
#pragma unroll
            for (int r = 0; r < 4; ++r) {
                int row = wr * 64 + m * 16 + g * 4 + r;
                float out = (acc[m][n][r] - st_fin[row][0]) * st_fin[row][1] * gv + bv;
                X[(mbase + row) * 256 + gcol] = f2us(out);
            }
        }
}

// ---------------------------------------------------------------------------
// MFMA attention: 1 wave per (node, head); 2 waves per block.
// S^T = mfma(K, Q)  (no transposes needed), softmax over C-rows (keys),
// O^T = mfma(V^T, P^T) with P in LDS [q][key], V^T staged by scalar writes.
// ---------------------------------------------------------------------------
__global__ __launch_bounds__(128) void attn_mfma(const ushort_t* __restrict__ qkv,
                                                 ushort_t* __restrict__ O) {
    __shared__ ushort_t smem[2][6912];   // per wave: vt [32][72] + pl [64][72]
    const int w = threadIdx.x >> 6, lane = threadIdx.x & 63;
    const int h = blockIdx.y * 2 + w;
    const int rl = lane & 15, g = lane >> 4;
    const size_t rowbase = (size_t)blockIdx.x * 64;
    ushort_t* vt = smem[w];
    ushort_t* pl = smem[w] + 2304;

    // stage V^T: vt[d][k]  (lane = key)
    const ushort_t* vp = qkv + (rowbase + lane) * 768 + 512 + h * 32;
#pragma unroll
    for (int i = 0; i < 4; ++i) {
        union { short8 v; ushort_t s[8]; } u;
        u.v = *(const short8*)(vp + i * 8);
#pragma unroll
        for (int j = 0; j < 8; ++j) vt[(i * 8 + j) * 72 + lane] = u.s[j];
    }

    // K (A-op) and Q (B-op) fragments directly from global
    short8 kf[4], qf[4];
#pragma unroll
    for (int t = 0; t < 4; ++t) {
        kf[t] = *(const short8*)(qkv + (rowbase + t * 16 + rl) * 768 + 256 + h * 32 + g * 8);
        qf[t] = *(const short8*)(qkv + (rowbase + t * 16 + rl) * 768 +       h * 32 + g * 8);
    }

    f32x4 s[4][4];
    const f32x4 fzero = {0.f, 0.f, 0.f, 0.f};
#pragma unroll
    for (int kt = 0; kt < 4; ++kt)
#pragma unroll
        for (int qt = 0; qt < 4; ++qt) s[kt][qt] = fzero;
#pragma unroll
    for (int kt = 0; kt < 4; ++kt)
#pragma unroll
        for (int qt = 0; qt < 4; ++qt)
            s[kt][qt] = __builtin_amdgcn_mfma_f32_16x16x32_bf16(kf[kt], qf[qt], s[kt][qt], 0, 0, 0);

    // softmax over keys for each of the 4 query cols held by this lane
    const float sc = 0.17677669529663687f;   // 1/sqrt(32)
    float inv[4];
#pragma unroll
    for (int qt = 0; qt < 4; ++qt) {
        float m = -1e30f;
#pragma unroll
        for (int kt = 0; kt < 4; ++kt)
#pragma unroll
            for (int r = 0; r < 4; ++r) { s[kt][qt][r] *= sc; m = fmaxf(m, s[kt][qt][r]); }
        m = fmaxf(m, __shfl_xor(m, 16));
        m = fmaxf(m, __shfl_xor(m, 32));
        float sum = 0.f;
#pragma unroll
        for (int kt = 0; kt < 4; ++kt)
#pragma unroll
            for (int r = 0; r < 4; ++r) { float e = __expf(s[kt][qt][r] - m); s[kt][qt][r] = e; sum += e; }
        sum += __shfl_xor(sum, 16);
        sum += __shfl_xor(sum, 32);
        inv[qt] = 1.f / sum;
    }

    // write normalized P to pl[q][key]
#pragma unroll
    for (int qt = 0; qt < 4; ++qt)
#pragma unroll
        for (int kt = 0; kt < 4; ++kt) {
            us4 pk;
#pragma unroll
            for (int r = 0; r < 4; ++r) pk[r] = f2us(s[kt][qt][r] * inv[qt]);
            *(us4*)&pl[(qt * 16 + rl) * 72 + kt * 16 + g * 4] = pk;
        }
    asm volatile("s_waitcnt lgkmcnt(0)" ::: "memory");
    __builtin_amdgcn_sched_barrier(0);

    // O^T = sum_k V^T[d,k] P^T[k,q]
    f32x4 o[2][4];
#pragma unroll
    for (int dt = 0; dt < 2; ++dt)
#pragma unroll
        for (int qt = 0; qt < 4; ++qt) o[dt][qt] = fzero;
#pragma unroll
    for (int ks = 0; ks < 2; ++ks) {
        short8 va[2];
#pragma unroll
        for (int dt = 0; dt < 2; ++dt)
            va[dt] = *(const short8*)&vt[(dt * 16 + rl) * 72 + ks * 32 + g * 8];
#pragma unroll
        for (int qt = 0; qt < 4; ++qt) {
            short8 pb = *(const short8*)&pl[(qt * 16 + rl) * 72 + ks * 32 + g * 8];
#pragma unroll
            for (int dt = 0; dt < 2; ++dt)
                o[dt][qt] = __builtin_amdgcn_mfma_f32_16x16x32_bf16(va[dt], pb, o[dt][qt], 0, 0, 0);
        }
    }

    // transpose O^T -> row-major via pl reuse as [64][40]
#pragma unroll
    for (int dt = 0; dt < 2; ++dt)
#pragma unroll
        for (int qt = 0; qt < 4; ++qt) {
            us4 ov;
#pragma unroll
            for (int r = 0; r < 4; ++r) ov[r] = f2us(o[dt][qt][r]);
            *(us4*)&pl[(qt * 16 + rl) * 40 + dt * 16 + g * 4] = ov;
        }
    asm volatile("s_waitcnt lgkmcnt(0)" ::: "memory");
    __builtin_amdgcn_sched_barrier(0);
    ushort_t* op = O + (rowbase + lane) * 256 + h * 32;
#pragma unroll
    for (int t = 0; t < 4; ++t)
        *(short8*)(op + t * 8) = *(const short8*)&pl[lane * 40 + t * 8];
}

// ---------------------------------------------------------------------------
__global__ void pe_kernel(float* __restrict__ pe) {
    int s = blockIdx.x, d = threadIdx.x;
    int i = d >> 1;
    float freq = __expf((float)(2 * i) * (-9.210340371976184f / 256.f));
    float ang = (float)s * freq;
    pe[s * DIM + d] = (d & 1) ? cosf(ang) : sinf(ang);
}

__global__ void embed_kernel(const void* __restrict__ tok_emb,
                             const int* __restrict__ flag,
                             const int* __restrict__ tokens,
                             const float* __restrict__ pe,
                             ushort_t* __restrict__ X, int row0) {
    int lr = blockIdx.x, d = threadIdx.x;
    int grow = row0 + lr;
    int tok = tokens[grow];
    int s = grow & 63;
    size_t idx = (size_t)tok * DIM + d;
    float tv = (*flag) ? us2f(((const ushort_t*)tok_emb)[idx])
                       : ((const float*)tok_emb)[idx];
    float v = tv * 16.f + pe[s * DIM + d];
    X[(size_t)lr * DIM + d] = f2us(v);
}

__global__ void mean_kernel(const ushort_t* __restrict__ Xc,
                            const ushort_t* __restrict__ type_emb,
                            const int* __restrict__ rtypes,
                            float* __restrict__ h, ushort_t* __restrict__ hb, int n0) {
    int nl = blockIdx.x, d = threadIdx.x;
    float acc = 0.f;
    for (int s = 0; s < 64; ++s) acc += us2f(Xc[((size_t)nl * 64 + s) * DIM + d]);
    int n = n0 + nl;
    float val = acc * (1.f / 64.f) + us2f(type_emb[(size_t)rtypes[n] * DIM + d]);
    h[(size_t)n * DIM + d] = val;
    hb[(size_t)n * DIM + d] = f2us(val);
}

// ---------------------------------------------------------------------------
// CSR build (by dst)
// ---------------------------------------------------------------------------
__global__ void hist_kernel(const int* __restrict__ ei, int* __restrict__ counts) {
    int e = blockIdx.x * 256 + threadIdx.x;
    if (e < EDGES) atomicAdd(&counts[ei[EDGES + e]], 1);
}
__global__ __launch_bounds__(256) void scan_kernel(const int* __restrict__ counts,
                                                   int* __restrict__ indptr,
                                                   int* __restrict__ cursor) {
    __shared__ int part[256];
    int t = threadIdx.x;
    int local[8]; int s = 0;
#pragma unroll
    for (int i = 0; i < 8; ++i) { local[i] = s; s += counts[t * 8 + i]; }
    part[t] = s;
    __syncthreads();
    for (int d = 1; d < 256; d <<= 1) {
        int val = (t >= d) ? part[t - d] : 0;
        __syncthreads();
        part[t] += val;
        __syncthreads();
    }
    int base = part[t] - s;
#pragma unroll
    for (int i = 0; i < 8; ++i) { int v = base + local[i]; indptr[t * 8 + i] = v; cursor[t * 8 + i] = v; }
    if (t == 255) indptr[NN] = part[255];
}
__global__ void scatter_kernel(const int* __restrict__ ei, const int* __restrict__ et,
                               int* __restrict__ cursor, int* __restrict__ col_src,
                               int* __restrict__ col_type) {
    int e = blockIdx.x * 256 + threadIdx.x;
    if (e < EDGES) {
        int d = ei[EDGES + e];
        int pp = atomicAdd(&cursor[d], 1);
        col_src[pp] = ei[e];
        col_type[pp] = et[e];
    }
}

__global__ __launch_bounds__(256) void asad_kernel(const float* __restrict__ xg,
                                                   const ushort_t* __restrict__ asrc,
                                                   const ushort_t* __restrict__ adst,
                                                   float* __restrict__ a_s, float* __restrict__ a_d,
                                                   int l) {
    int n = blockIdx.x, g = threadIdx.x >> 6, lane = threadIdx.x & 63;
    const float* xp = xg + (size_t)n * 1024 + g * 256 + lane * 4;
    const ushort_t* sp = asrc + ((size_t)l * 4 + g) * 256 + lane * 4;
    const ushort_t* dp = adst + ((size_t)l * 4 + g) * 256 + lane * 4;
    float ss = 0.f, dd = 0.f;
#pragma unroll
    for (int j = 0; j < 4; ++j) { float x = xp[j]; ss += x * us2f(sp[j]); dd += x * us2f(dp[j]); }
#pragma unroll
    for (int off = 32; off > 0; off >>= 1) { ss += __shfl_xor(ss, off); dd += __shfl_xor(dd, off); }
    if (lane == 0) { a_s[n * 4 + g] = ss; a_d[n * 4 + g] = dd; }
}

__global__ __launch_bounds__(256) void edge_kernel(const float* __restrict__ xg,
                                                   const float* __restrict__ a_s,
                                                   const float* __restrict__ a_d,
                                                   const int* __restrict__ indptr,
                                                   const int* __restrict__ col_src,
                                                   const int* __restrict__ col_type,
                                                   const ushort_t* __restrict__ gat_b,
                                                   float* __restrict__ h_new, int l, int r) {
    __shared__ float outs[4][256];
    int n = blockIdx.x, g = threadIdx.x >> 6, lane = threadIdx.x & 63;
    int beg = indptr[n], end = indptr[n + 1];
    float adn = a_d[n * 4 + g];
    float eself = lrelu02(a_s[n * 4 + g] + adn);
    float m = eself;
    for (int e = beg; e < end; ++e) {
        if (col_type[e] == r) {
            float v = lrelu02(a_s[col_src[e] * 4 + g] + adn);
            m = fmaxf(m, v);
        }
    }
    float wself = __expf(eself - m);
    float denom = wself;
    const float* xn = xg + (size_t)n * 1024 + g * 256 + lane * 4;
    float num[4];
#pragma unroll
    for (int j = 0; j < 4; ++j) num[j] = wself * xn[j];
    for (int e = beg; e < end; ++e) {
        if (col_type[e] == r) {
            int src = col_src[e];
            float v = lrelu02(a_s[src * 4 + g] + adn);
            float w = __expf(v - m);
            denom += w;
            const float* xs = xg + (size_t)src * 1024 + g * 256 + lane * 4;
#pragma unroll
            for (int j = 0; j < 4; ++j) num[j] += w * xs[j];
        }
    }
    float invd = 1.f / denom;
#pragma unroll
    for (int j = 0; j < 4; ++j) outs[g][lane * 4 + j] = num[j] * invd;
    __syncthreads();
    int d = threadIdx.x;
    float hv = 0.25f * (outs[0][d] + outs[1][d] + outs[2][d] + outs[3][d]) + us2f(gat_b[l * 256 + d]);
    h_new[(size_t)n * 256 + d] += hv;
}

__global__ void update_h_kernel(float* __restrict__ h, const float* __restrict__ h_new,
                                ushort_t* __restrict__ hb) {
    size_t i = (size_t)blockIdx.x * 256 + threadIdx.x;
    float v = fmaxf(h[i] + h_new[i], 0.f);
    h[i] = v;
    hb[i] = f2us(v);
}

__global__ __launch_bounds__(64) void final_kernel(const float* __restrict__ pos,
                                                   const ushort_t* __restrict__ log_c,
                                                   const int* __restrict__ flag,
                                                   void* __restrict__ out) {
    int n = blockIdx.x, lane = threadIdx.x;
    int bf = *flag;
    float scv = sqrtf(__expf(us2f(log_c[0])));
    f32x4 pv = *(const f32x4*)&pos[(size_t)n * 256 + lane * 4];
    float st[4]; float sq = 0.f;
#pragma unroll
    for (int j = 0; j < 4; ++j) { float t = tanhf(pv[j]) * 2.f * scv; st[j] = t; sq += t * t; }
#pragma unroll
    for (int off = 32; off > 0; off >>= 1) sq += __shfl_xor(sq, off);
    float rr = fmaxf(sqrtf(sq), 1e-8f);
    float sf = sinhf(rr) / rr;
    if (bf) {
        ushort_t* o = (ushort_t*)out;
        if (lane == 0) o[(size_t)n * 257] = f2us(coshf(rr));
#pragma unroll
        for (int j = 0; j < 4; ++j) o[(size_t)n * 257 + 1 + lane * 4 + j] = f2us(sf * st[j]);
    } else {
        float* o = (float*)out;
        if (lane == 0) o[(size_t)n * 257] = coshf(rr);
#pragma unroll
        for (int j = 0; j < 4; ++j) o[(size_t)n * 257 + 1 + lane * 4 + j] = sf * st[j];
    }
}

// ---------------------------------------------------------------------------
extern "C" void kernel_launch(void* const* d_in, const int* in_sizes, int n_in,
                              void* d_out, int out_size, void* d_ws, size_t ws_size,
                              hipStream_t stream) {
    const int* tokens = (const int*)d_in[25];
    const int* rtypes = (const int*)d_in[26];
    const int* eidx   = (const int*)d_in[27];
    const int* etype  = (const int*)d_in[28];

    char* p = (char*)d_ws;
    auto alloc = [&](size_t b) -> char* { char* r = p; p += (b + 255) & ~(size_t)255; return r; };

    int* flag = (int*)alloc(256);

    // ---- build conversion table (weights -> canonical bf16, B^T for GEMMs)
    ConvArgs ca;
    int ne = 0; unsigned int off = 0;
    auto add = [&](const void* src, unsigned int soff, unsigned int elems,
                   int klog2, int ncol) -> unsigned int {
        ca.src[ne] = src; ca.soff[ne] = soff; ca.off[ne] = off;
        ca.nel[ne] = elems; ca.klog2[ne] = (unsigned char)klog2;
        ca.ncol[ne] = (unsigned short)ncol;
        unsigned int r = off; off += (elems + 7) & ~7u; ++ne; return r;
    };
    unsigned int oWqkv = add(d_in[1], 0, 196608, 8, 768);        // l0: [768][256]
                         add(d_in[1], 196608, 196608, 8, 768);   // l1
    unsigned int obqkv = add(d_in[2], 0, 1536, 0, 0);
    unsigned int oWo   = add(d_in[3], 0, 65536, 8, 256);
                         add(d_in[3], 65536, 65536, 8, 256);
    unsigned int obo   = add(d_in[4], 0, 512, 0, 0);
    unsigned int oln1g = add(d_in[5], 0, 512, 0, 0);
    unsigned int oln1b = add(d_in[6], 0, 512, 0, 0);
    unsigned int oln2g = add(d_in[7], 0, 512, 0, 0);
    unsigned int oln2b = add(d_in[8], 0, 512, 0, 0);
    unsigned int oW1   = add(d_in[9], 0, 65536, 8, 256);
                         add(d_in[9], 65536, 65536, 8, 256);
    unsigned int ob1   = add(d_in[10], 0, 512, 0, 0);
    unsigned int oW2   = add(d_in[11], 0, 65536, 8, 256);
                         add(d_in[11], 65536, 65536, 8, 256);
    unsigned int ob2   = add(d_in[12], 0, 512, 0, 0);
    unsigned int otype = add(d_in[13], 0, 2560, 0, 0);
    unsigned int omsgW = add(d_in[14], 0, 65536, 8, 256);
                         add(d_in[14], 65536, 65536, 8, 256);
                         add(d_in[14], 131072, 65536, 8, 256);
    unsigned int omsgb = add(d_in[15], 0, 768, 0, 0);
    unsigned int ogatW = add(d_in[16], 0, 262144, 8, 1024);
                         add(d_in[16], 262144, 262144, 8, 1024);
                         add(d_in[16], 524288, 262144, 8, 1024);
                         add(d_in[16], 786432, 262144, 8, 1024);
    unsigned int ogatb = add(d_in[17], 0, 1024, 0, 0);
    unsigned int oasrc = add(d_in[18], 0, 4096, 0, 0);
    unsigned int oadst = add(d_in[19], 0, 4096, 0, 0);
    unsigned int ospW1 = add(d_in[20], 0, 131072, 8, 512);       // [512][256]
    unsigned int ospb1 = add(d_in[21], 0, 512, 0, 0);
    unsigned int ospW2 = add(d_in[22], 0, 131072, 9, 256);       // [256][512]
    unsigned int ospb2 = add(d_in[23], 0, 256, 0, 0);
    unsigned int ologc = add(d_in[24], 0, 1, 0, 0);
    ca.off[ne] = off;
    unsigned int wtotal = off;

    ushort_t* wtb    = (ushort_t*)alloc((size_t)wtotal * 2);
    float*    pe     = (float*)   alloc((size_t)SEQL * DIM * 4);
    ushort_t* Xc     = (ushort_t*)alloc((size_t)CROWS * DIM * 2);
    ushort_t* QKV    = (ushort_t*)alloc((size_t)CROWS * 768 * 2);
    ushort_t* Oc     = (ushort_t*)alloc((size_t)CROWS * DIM * 2);
    float*    h      = (float*)   alloc((size_t)NN * DIM * 4);
    ushort_t* hb     = (ushort_t*)alloc((size_t)NN * DIM * 2);
    float*    hnew   = (float*)   alloc((size_t)NN * DIM * 4);
    ushort_t* th     = (ushort_t*)alloc((size_t)NN * DIM * 2);
    float*    xg     = (float*)   alloc((size_t)NN * 1024 * 4);
    float*    a_s    = (float*)   alloc((size_t)NN * 4 * 4);
    float*    a_d    = (float*)   alloc((size_t)NN * 4 * 4);
    ushort_t* thead  = (ushort_t*)alloc((size_t)NN * 512 * 2);
    float*    posb   = (float*)   alloc((size_t)NN * DIM * 4);
    int*      counts = (int*)     alloc((size_t)NN * 4);
    int*      indptr = (int*)     alloc((size_t)(NN + 1) * 4);
    int*      cursor = (int*)     alloc((size_t)NN * 4);
    int*      col_src  = (int*)   alloc((size_t)EDGES * 4);
    int*      col_type = (int*)   alloc((size_t)EDGES * 4);

    const ushort_t* WqkvT = wtb + oWqkv;
    const ushort_t* bqkv  = wtb + obqkv;
    const ushort_t* WoT   = wtb + oWo;
    const ushort_t* bo    = wtb + obo;
    const ushort_t* ln1g  = wtb + oln1g;
    const ushort_t* ln1b  = wtb + oln1b;
    const ushort_t* ln2g  = wtb + oln2g;
    const ushort_t* ln2b  = wtb + oln2b;
    const ushort_t* W1T   = wtb + oW1;
    const ushort_t* b1    = wtb + ob1;
    const ushort_t* W2T   = wtb + oW2;
    const ushort_t* b2    = wtb + ob2;
    const ushort_t* type_emb = wtb + otype;
    const ushort_t* msgWT = wtb + omsgW;
    const ushort_t* msg_b = wtb + omsgb;
    const ushort_t* gatWT = wtb + ogatW;
    const ushort_t* gat_b = wtb + ogatb;
    const ushort_t* gasrc = wtb + oasrc;
    const ushort_t* gadst = wtb + oadst;
    const ushort_t* spW1T = wtb + ospW1;
    const ushort_t* spb1  = wtb + ospb1;
    const ushort_t* spW2T = wtb + ospW2;
    const ushort_t* spb2  = wtb + ospb2;
    const ushort_t* log_c = wtb + ologc;

    sniff_kernel<<<1, 256, 0, stream>>>((const unsigned int*)d_in[1], flag);
    convert_kernel<<<2048, 256, 0, stream>>>(ca, flag, wtb, wtotal);

    pe_kernel<<<SEQL, DIM, 0, stream>>>(pe);
    hipMemsetAsync(counts, 0, NN * 4, stream);
    hist_kernel<<<EDGES / 256, 256, 0, stream>>>(eidx, counts);
    scan_kernel<<<1, 256, 0, stream>>>(counts, indptr, cursor);
    scatter_kernel<<<EDGES / 256, 256, 0, stream>>>(eidx, etype, cursor, col_src, col_type);

    for (int c = 0; c < CHUNKS; ++c) {
        int row0 = c * CROWS;
        embed_kernel<<<CROWS, DIM, 0, stream>>>(d_in[0], flag, tokens, pe, Xc, row0);
        for (int l = 0; l < 2; ++l) {
            gemm_bt<false, true><<<dim3(CROWS / 128, 6), 256, 0, stream>>>(
                Xc, WqkvT + (size_t)l * 196608, bqkv + l * 768, QKV, CROWS, 768, DIM);
            attn_mfma<<<dim3(CN, 4), 128, 0, stream>>>(QKV, Oc);
            gemm_ln<<<CROWS / 128, 512, 0, stream>>>(
                Oc, WoT + (size_t)l * 65536, bo + l * DIM, Xc, ln1g + l * DIM, ln1b + l * DIM, DIM);
            gemm_bt<true, true><<<dim3(CROWS / 128, 2), 256, 0, stream>>>(
                Xc, W1T + (size_t)l * 65536, b1 + l * DIM, Oc, CROWS, DIM, DIM);
            gemm_ln<<<CROWS / 128, 512, 0, stream>>>(
                Oc, W2T + (size_t)l * 65536, b2 + l * DIM, Xc, ln2g + l * DIM, ln2b + l * DIM, DIM);
        }
        mean_kernel<<<CN, DIM, 0, stream>>>(Xc, type_emb, rtypes, h, hb, c * CN);
    }

    for (int l = 0; l < 4; ++l) {
        hipMemsetAsync(hnew, 0, (size_t)NN * DIM * 4, stream);
        for (int r = 0; r < 3; ++r) {
            gemm_bt<false, true><<<dim3(NN / 128, 2), 256, 0, stream>>>(
                hb, msgWT + (size_t)r * 65536, msg_b + r * DIM, th, NN, DIM, DIM);
            gemm_bt<false, false><<<dim3(NN / 128, 8), 256, 0, stream>>>(
                th, gatWT + (size_t)l * 262144, nullptr, xg, NN, 1024, DIM);
            asad_kernel<<<NN, 256, 0, stream>>>(xg, gasrc, gadst, a_s, a_d, l);
            edge_kernel<<<NN, 256, 0, stream>>>(xg, a_s, a_d, indptr, col_src, col_type,
                                                gat_b, hnew, l, r);
        }
        update_h_kernel<<<NN, 256, 0, stream>>>(h, hnew, hb);
    }

    gemm_bt<true, true><<<dim3(NN / 128, 4), 256, 0, stream>>>(hb, spW1T, spb1, thead, NN, 512, DIM);
    gemm_bt<false, false><<<dim3(NN / 128, 2), 256, 0, stream>>>(thead, spW2T, spb2, posb, NN, DIM, 512);
    final_kernel<<<NN, 64, 0, stream>>>(posb, log_c, flag, d_out);
}

// Round 4
// 1264.094 us; speedup vs baseline: 2.2492x; 1.2550x over previous
//
#include <hip/hip_runtime.h>
#include <hip/hip_bf16.h>

#define NN 2048
#define SEQL 64
#define DIM 256
#define NHEAD 8
#define EDGES 32768
#define CHUNKS 2
#define CN (NN / CHUNKS)          // 1024 nodes per chunk
#define CROWS (CN * SEQL)         // 65536 rows per chunk

typedef __attribute__((ext_vector_type(8))) short short8;
typedef __attribute__((ext_vector_type(4))) float f32x4;
typedef __attribute__((ext_vector_type(4))) unsigned short us4;
typedef unsigned short ushort_t;

__device__ __forceinline__ float us2f(unsigned short u) {
    union { unsigned int i; float f; } x; x.i = ((unsigned int)u) << 16; return x.f;
}
__device__ __forceinline__ unsigned short f2us(float f) {
    union { float f; unsigned int i; } u; u.f = f;
    unsigned int r = u.i + 0x7fffu + ((u.i >> 16) & 1u);
    return (unsigned short)(r >> 16);
}
__device__ __forceinline__ float lrelu02(float v) { return v < 0.f ? 0.2f * v : v; }

// async global->LDS, 16B per lane; LDS dest must be wave-uniform base
__device__ __forceinline__ void gload_lds16(const void* g, void* l) {
    __builtin_amdgcn_global_load_lds(
        (const __attribute__((address_space(1))) unsigned int*)g,
        (__attribute__((address_space(3))) unsigned int*)l, 16, 0, 0);
}

// ---------------------------------------------------------------------------
// dtype sniff (bf16-packed vs f32 inputs)
// ---------------------------------------------------------------------------
__global__ void sniff_kernel(const unsigned int* __restrict__ w, int* __restrict__ flag) {
    __shared__ int cnt;
    if (threadIdx.x == 0) cnt = 0;
    __syncthreads();
    unsigned int v = w[(size_t)threadIdx.x * 509];
    unsigned int e_lo = (v >> 7) & 0xffu;
    if (e_lo >= 0x6eu && e_lo <= 0x7fu) atomicAdd(&cnt, 1);
    __syncthreads();
    if (threadIdx.x == 0) *flag = (cnt > 128) ? 1 : 0;   // 1 = inputs are bf16
}

// ---------------------------------------------------------------------------
// Weight canonicalization to bf16, with optional per-slice transpose
// ---------------------------------------------------------------------------
#define NE 33
struct ConvArgs {
    const void* src[NE];
    unsigned int soff[NE];
    unsigned int off[NE + 1];
    unsigned int nel[NE];
    unsigned short ncol[NE];
    unsigned char klog2[NE];
};

__global__ void convert_kernel(ConvArgs a, const int* __restrict__ flag,
                               ushort_t* __restrict__ dst, unsigned int total) {
    const int bf = *flag;
    for (unsigned int i = blockIdx.x * 256 + threadIdx.x; i < total; i += gridDim.x * 256) {
        int e = 0;
        while (a.off[e + 1] <= i) ++e;
        unsigned int j = i - a.off[e];
        ushort_t v = 0;
        if (j < a.nel[e]) {
            unsigned int sidx;
            if (a.klog2[e]) {
                unsigned int K = 1u << a.klog2[e];
                unsigned int k = j & (K - 1), n = j >> a.klog2[e];
                sidx = k * (unsigned int)a.ncol[e] + n;
            } else sidx = j;
            sidx += a.soff[e];
            if (bf) v = ((const ushort_t*)a.src[e])[sidx];
            else    v = f2us(((const float*)a.src[e])[sidx]);
        }
        dst[i] = v;
    }
}

// ---------------------------------------------------------------------------
// bf16 MFMA GEMM, pre-transposed B, global_load_lds staging (m97 structure).
// C[z][M,N] = A[z][M,K] @ BT[N,K]^T (+bias)(+relu). K%32==0, M%128==0, N%128==0
// ---------------------------------------------------------------------------
template <bool RELU, bool OUT_BF16>
__global__ __launch_bounds__(256) void gemm_bt(
    const ushort_t* __restrict__ A, const ushort_t* __restrict__ BT,
    const ushort_t* __restrict__ bias, void* __restrict__ C,
    int M, int N, int K, int lda, size_t a_off_z, size_t c_off_z)
{
    __shared__ __align__(16) short a_lds[128][32];
    __shared__ __align__(16) short b_lds[128][32];

    const int tid  = threadIdx.x;
    const int lane = tid & 63;
    const int wave = tid >> 6;
    const int wr = wave >> 1, wc = wave & 1;
    const size_t mbase = (size_t)blockIdx.x * 128;
    const size_t nbase = (size_t)blockIdx.y * 128;
    A += (size_t)blockIdx.z * a_off_z;
    const size_t czoff = (size_t)blockIdx.z * c_off_z;

    f32x4 acc[4][4];
    const f32x4 fzero = {0.f, 0.f, 0.f, 0.f};
#pragma unroll
    for (int i = 0; i < 4; ++i)
#pragma unroll
        for (int j = 0; j < 4; ++j) acc[i][j] = fzero;

    const int srow = tid >> 2;          // 0..63
    const int skc  = (tid & 3) * 8;
    short* lbA = &a_lds[0][0] + wave * 512;   // wave*1024 bytes
    short* lbB = &b_lds[0][0] + wave * 512;
    const int rl = lane & 15;
    const int kf = (lane >> 4) * 8;

    for (int k0 = 0; k0 < K; k0 += 32) {
        __syncthreads();
        gload_lds16(A  + (mbase + srow)      * (size_t)lda + k0 + skc, lbA);
        gload_lds16(A  + (mbase + srow + 64) * (size_t)lda + k0 + skc, lbA + 2048);
        gload_lds16(BT + (nbase + srow)      * (size_t)K   + k0 + skc, lbB);
        gload_lds16(BT + (nbase + srow + 64) * (size_t)K   + k0 + skc, lbB + 2048);
        __syncthreads();

        short8 af[4], bfr[4];
#pragma unroll
        for (int m = 0; m < 4; ++m) af[m]  = *(const short8*)&a_lds[wr * 64 + m * 16 + rl][kf];
#pragma unroll
        for (int n = 0; n < 4; ++n) bfr[n] = *(const short8*)&b_lds[wc * 64 + n * 16 + rl][kf];
#pragma unroll
        for (int m = 0; m < 4; ++m)
#pragma unroll
            for (int n = 0; n < 4; ++n)
                acc[m][n] = __builtin_amdgcn_mfma_f32_16x16x32_bf16(af[m], bfr[n], acc[m][n], 0, 0, 0);
    }

    const int rq = (lane >> 4) * 4;
#pragma unroll
    for (int m = 0; m < 4; ++m) {
#pragma unroll
        for (int n = 0; n < 4; ++n) {
            size_t gcol = nbase + wc * 64 + n * 16 + rl;
            float bv = bias ? us2f(bias[gcol]) : 0.f;
#pragma unroll
            for (int q = 0; q < 4; ++q) {
                size_t grow = mbase + wr * 64 + m * 16 + rq + q;
                float v = acc[m][n][q] + bv;
                if (RELU) v = fmaxf(v, 0.f);
                if (OUT_BF16) ((ushort_t*)C)[czoff + grow * N + gcol] = f2us(v);
                else          ((float*)C)[czoff + grow * N + gcol] = v;
            }
        }
    }
}

// ---------------------------------------------------------------------------
// Fused GEMM + residual + LayerNorm (N=256): X = LN(X + A@BT^T + bias)*g + b
// tile 128x256, 512 threads (8 waves 2x4), global_load_lds staging
// ---------------------------------------------------------------------------
__global__ __launch_bounds__(512) void gemm_ln(
    const ushort_t* __restrict__ A, const ushort_t* __restrict__ BT,
    const ushort_t* __restrict__ bias, ushort_t* __restrict__ X,
    const ushort_t* __restrict__ gg, const ushort_t* __restrict__ bb, int K)
{
    __shared__ __align__(16) short a_lds[128][32];
    __shared__ __align__(16) short b_lds[256][32];
    __shared__ float st_part[128][8];
    __shared__ float st_fin[128][2];

    const int tid  = threadIdx.x;
    const int lane = tid & 63;
    const int wave = tid >> 6;
    const int wr = wave >> 2, wc = wave & 3;
    const size_t mbase = (size_t)blockIdx.x * 128;

    f32x4 acc[4][4];
    const f32x4 fzero = {0.f, 0.f, 0.f, 0.f};
#pragma unroll
    for (int i = 0; i < 4; ++i)
#pragma unroll
        for (int j = 0; j < 4; ++j) acc[i][j] = fzero;

    const int srow = tid >> 2;          // 0..127
    const int skc  = (tid & 3) * 8;
    short* lbA = &a_lds[0][0] + wave * 512;
    short* lbB = &b_lds[0][0] + wave * 512;
    const int rl = lane & 15;
    const int g  = lane >> 4;
    const int kf = g * 8;

    for (int k0 = 0; k0 < K; k0 += 32) {
        __syncthreads();
        gload_lds16(A  + (mbase + srow) * (size_t)K + k0 + skc, lbA);
        gload_lds16(BT + (size_t)srow         * K + k0 + skc, lbB);
        gload_lds16(BT + (size_t)(srow + 128) * K + k0 + skc, lbB + 4096);
        __syncthreads();

        short8 af[4], bfr[4];
#pragma unroll
        for (int m = 0; m < 4; ++m) af[m]  = *(const short8*)&a_lds[wr * 64 + m * 16 + rl][kf];
#pragma unroll
        for (int n = 0; n < 4; ++n) bfr[n] = *(const short8*)&b_lds[wc * 64 + n * 16 + rl][kf];
#pragma unroll
        for (int m = 0; m < 4; ++m)
#pragma unroll
            for (int n = 0; n < 4; ++n)
                acc[m][n] = __builtin_amdgcn_mfma_f32_16x16x32_bf16(af[m], bfr[n], acc[m][n], 0, 0, 0);
    }

#pragma unroll
    for (int m = 0; m < 4; ++m)
#pragma unroll
        for (int n = 0; n < 4; ++n) {
            int gcol = wc * 64 + n * 16 + rl;
            float bv = us2f(bias[gcol]);
#pragma unroll
            for (int r = 0; r < 4; ++r) {
                size_t grow = mbase + wr * 64 + m * 16 + g * 4 + r;
                acc[m][n][r] += bv + us2f(X[grow * 256 + gcol]);
            }
        }
#pragma unroll
    for (int m = 0; m < 4; ++m)
#pragma unroll
        for (int r = 0; r < 4; ++r) {
            float ps = 0.f, pq = 0.f;
#pragma unroll
            for (int n = 0; n < 4; ++n) { float v = acc[m][n][r]; ps += v; pq += v * v; }
#pragma unroll
            for (int off = 1; off < 16; off <<= 1) { ps += __shfl_xor(ps, off); pq += __shfl_xor(pq, off); }
            if (rl == 0) {
                int row = wr * 64 + m * 16 + g * 4 + r;
                st_part[row][wc] = ps;
                st_part[row][4 + wc] = pq;
            }
        }
    __syncthreads();
    if (tid < 128) {
        float s = st_part[tid][0] + st_part[tid][1] + st_part[tid][2] + st_part[tid][3];
        float q = st_part[tid][4] + st_part[tid][5] + st_part[tid][6] + st_part[tid][7];
        float mean = s * (1.f / 256.f);
        float var = q * (1.f / 256.f) - mean * mean;
        st_fin[tid][0] = mean;
        st_fin[tid][1] = rsqrtf(var + 1e-5f);
    }
    __syncthreads();
#pragma unroll
    for (int m = 0; m < 4; ++m)
#pragma unroll
        for (int n = 0; n < 4; ++n) {
            int gcol = wc * 64 + n * 16 + rl;
            float gv = us2f(gg[gcol]), bv = us2f(bb[gcol]);
#pragma unroll
            for (int r = 0; r < 4; ++r) {
                int row = wr * 64 + m * 16 + g * 4 + r;
                float out = (acc[m][n][r] - st_fin[row][0]) * st_fin[row][1] * gv + bv;
                X[(mbase + row) * 256 + gcol] = f2us(out);
            }
        }
}

// ---------------------------------------------------------------------------
// MFMA attention: 1 wave per (node, head); 2 waves per block.
// ---------------------------------------------------------------------------
__global__ __launch_bounds__(128) void attn_mfma(const ushort_t* __restrict__ qkv,
                                                 ushort_t* __restrict__ O) {
    __shared__ ushort_t smem[2][6912];
    const int w = threadIdx.x >> 6, lane = threadIdx.x & 63;
    const int h = blockIdx.y * 2 + w;
    const int rl = lane & 15, g = lane >> 4;
    const size_t rowbase = (size_t)blockIdx.x * 64;
    ushort_t* vt = smem[w];
    ushort_t* pl = smem[w] + 2304;

    const ushort_t* vp = qkv + (rowbase + lane) * 768 + 512 + h * 32;
#pragma unroll
    for (int i = 0; i < 4; ++i) {
        union { short8 v; ushort_t s[8]; } u;
        u.v = *(const short8*)(vp + i * 8);
#pragma unroll
        for (int j = 0; j < 8; ++j) vt[(i * 8 + j) * 72 + lane] = u.s[j];
    }

    short8 kf[4], qf[4];
#pragma unroll
    for (int t = 0; t < 4; ++t) {
        kf[t] = *(const short8*)(qkv + (rowbase + t * 16 + rl) * 768 + 256 + h * 32 + g * 8);
        qf[t] = *(const short8*)(qkv + (rowbase + t * 16 + rl) * 768 +       h * 32 + g * 8);
    }

    f32x4 s[4][4];
    const f32x4 fzero = {0.f, 0.f, 0.f, 0.f};
#pragma unroll
    for (int kt = 0; kt < 4; ++kt)
#pragma unroll
        for (int qt = 0; qt < 4; ++qt) s[kt][qt] = fzero;
#pragma unroll
    for (int kt = 0; kt < 4; ++kt)
#pragma unroll
        for (int qt = 0; qt < 4; ++qt)
            s[kt][qt] = __builtin_amdgcn_mfma_f32_16x16x32_bf16(kf[kt], qf[qt], s[kt][qt], 0, 0, 0);

    const float sc = 0.17677669529663687f;
    float inv[4];
#pragma unroll
    for (int qt = 0; qt < 4; ++qt) {
        float m = -1e30f;
#pragma unroll
        for (int kt = 0; kt < 4; ++kt)
#pragma unroll
            for (int r = 0; r < 4; ++r) { s[kt][qt][r] *= sc; m = fmaxf(m, s[kt][qt][r]); }
        m = fmaxf(m, __shfl_xor(m, 16));
        m = fmaxf(m, __shfl_xor(m, 32));
        float sum = 0.f;
#pragma unroll
        for (int kt = 0; kt < 4; ++kt)
#pragma unroll
            for (int r = 0; r < 4; ++r) { float e = __expf(s[kt][qt][r] - m); s[kt][qt][r] = e; sum += e; }
        sum += __shfl_xor(sum, 16);
        sum += __shfl_xor(sum, 32);
        inv[qt] = 1.f / sum;
    }

#pragma unroll
    for (int qt = 0; qt < 4; ++qt)
#pragma unroll
        for (int kt = 0; kt < 4; ++kt) {
            us4 pk;
#pragma unroll
            for (int r = 0; r < 4; ++r) pk[r] = f2us(s[kt][qt][r] * inv[qt]);
            *(us4*)&pl[(qt * 16 + rl) * 72 + kt * 16 + g * 4] = pk;
        }
    asm volatile("s_waitcnt lgkmcnt(0)" ::: "memory");
    __builtin_amdgcn_sched_barrier(0);

    f32x4 o[2][4];
#pragma unroll
    for (int dt = 0; dt < 2; ++dt)
#pragma unroll
        for (int qt = 0; qt < 4; ++qt) o[dt][qt] = fzero;
#pragma unroll
    for (int ks = 0; ks < 2; ++ks) {
        short8 va[2];
#pragma unroll
        for (int dt = 0; dt < 2; ++dt)
            va[dt] = *(const short8*)&vt[(dt * 16 + rl) * 72 + ks * 32 + g * 8];
#pragma unroll
        for (int qt = 0; qt < 4; ++qt) {
            short8 pb = *(const short8*)&pl[(qt * 16 + rl) * 72 + ks * 32 + g * 8];
#pragma unroll
            for (int dt = 0; dt < 2; ++dt)
                o[dt][qt] = __builtin_amdgcn_mfma_f32_16x16x32_bf16(va[dt], pb, o[dt][qt], 0, 0, 0);
        }
    }

#pragma unroll
    for (int dt = 0; dt < 2; ++dt)
#pragma unroll
        for (int qt = 0; qt < 4; ++qt) {
            us4 ov;
#pragma unroll
            for (int r = 0; r < 4; ++r) ov[r] = f2us(o[dt][qt][r]);
            *(us4*)&pl[(qt * 16 + rl) * 40 + dt * 16 + g * 4] = ov;
        }
    asm volatile("s_waitcnt lgkmcnt(0)" ::: "memory");
    __builtin_amdgcn_sched_barrier(0);
    ushort_t* op = O + (rowbase + lane) * 256 + h * 32;
#pragma unroll
    for (int t = 0; t < 4; ++t)
        *(short8*)(op + t * 8) = *(const short8*)&pl[lane * 40 + t * 8];
}

// ---------------------------------------------------------------------------
__global__ void pe_kernel(float* __restrict__ pe) {
    int s = blockIdx.x, d = threadIdx.x;
    int i = d >> 1;
    float freq = __expf((float)(2 * i) * (-9.210340371976184f / 256.f));
    float ang = (float)s * freq;
    pe[s * DIM + d] = (d & 1) ? cosf(ang) : sinf(ang);
}

__global__ void embed_kernel(const void* __restrict__ tok_emb,
                             const int* __restrict__ flag,
                             const int* __restrict__ tokens,
                             const float* __restrict__ pe,
                             ushort_t* __restrict__ X, int row0) {
    int lr = blockIdx.x, d = threadIdx.x;
    int grow = row0 + lr;
    int tok = tokens[grow];
    int s = grow & 63;
    size_t idx = (size_t)tok * DIM + d;
    float tv = (*flag) ? us2f(((const ushort_t*)tok_emb)[idx])
                       : ((const float*)tok_emb)[idx];
    float v = tv * 16.f + pe[s * DIM + d];
    X[(size_t)lr * DIM + d] = f2us(v);
}

__global__ void mean_kernel(const ushort_t* __restrict__ Xc,
                            const ushort_t* __restrict__ type_emb,
                            const int* __restrict__ rtypes,
                            float* __restrict__ h, ushort_t* __restrict__ hb, int n0) {
    int nl = blockIdx.x, d = threadIdx.x;
    float acc = 0.f;
    for (int s = 0; s < 64; ++s) acc += us2f(Xc[((size_t)nl * 64 + s) * DIM + d]);
    int n = n0 + nl;
    float val = acc * (1.f / 64.f) + us2f(type_emb[(size_t)rtypes[n] * DIM + d]);
    h[(size_t)n * DIM + d] = val;
    hb[(size_t)n * DIM + d] = f2us(val);
}

// ---------------------------------------------------------------------------
// CSR build (by dst)
// ---------------------------------------------------------------------------
__global__ void hist_kernel(const int* __restrict__ ei, int* __restrict__ counts) {
    int e = blockIdx.x * 256 + threadIdx.x;
    if (e < EDGES) atomicAdd(&counts[ei[EDGES + e]], 1);
}
__global__ __launch_bounds__(256) void scan_kernel(const int* __restrict__ counts,
                                                   int* __restrict__ indptr,
                                                   int* __restrict__ cursor) {
    __shared__ int part[256];
    int t = threadIdx.x;
    int local[8]; int s = 0;
#pragma unroll
    for (int i = 0; i < 8; ++i) { local[i] = s; s += counts[t * 8 + i]; }
    part[t] = s;
    __syncthreads();
    for (int d = 1; d < 256; d <<= 1) {
        int val = (t >= d) ? part[t - d] : 0;
        __syncthreads();
        part[t] += val;
        __syncthreads();
    }
    int base = part[t] - s;
#pragma unroll
    for (int i = 0; i < 8; ++i) { int v = base + local[i]; indptr[t * 8 + i] = v; cursor[t * 8 + i] = v; }
    if (t == 255) indptr[NN] = part[255];
}
__global__ void scatter_kernel(const int* __restrict__ ei, const int* __restrict__ et,
                               int* __restrict__ cursor, int* __restrict__ col_src,
                               int* __restrict__ col_type) {
    int e = blockIdx.x * 256 + threadIdx.x;
    if (e < EDGES) {
        int d = ei[EDGES + e];
        int pp = atomicAdd(&cursor[d], 1);
        col_src[pp] = ei[e];
        col_type[pp] = et[e];
    }
}

// a_s/a_d: grid (NN, 3), block 256 = 4 head-waves
__global__ __launch_bounds__(256) void asad_kernel(const float* __restrict__ xg,
                                                   const ushort_t* __restrict__ asrc,
                                                   const ushort_t* __restrict__ adst,
                                                   float* __restrict__ a_s, float* __restrict__ a_d,
                                                   int l) {
    int n = blockIdx.x, r = blockIdx.y, g = threadIdx.x >> 6, lane = threadIdx.x & 63;
    const float* xp = xg + ((size_t)r * NN + n) * 1024 + g * 256 + lane * 4;
    const ushort_t* sp = asrc + ((size_t)l * 4 + g) * 256 + lane * 4;
    const ushort_t* dp = adst + ((size_t)l * 4 + g) * 256 + lane * 4;
    float ss = 0.f, dd = 0.f;
#pragma unroll
    for (int j = 0; j < 4; ++j) { float x = xp[j]; ss += x * us2f(sp[j]); dd += x * us2f(dp[j]); }
#pragma unroll
    for (int off = 32; off > 0; off >>= 1) { ss += __shfl_xor(ss, off); dd += __shfl_xor(dd, off); }
    if (lane == 0) {
        a_s[((size_t)r * NN + n) * 4 + g] = ss;
        a_d[((size_t)r * NN + n) * 4 + g] = dd;
    }
}

// GAT edge-softmax + aggregate: grid (NN, 3); writes hnew3[r] (no memset)
__global__ __launch_bounds__(256) void edge_kernel(const float* __restrict__ xg,
                                                   const float* __restrict__ a_s,
                                                   const float* __restrict__ a_d,
                                                   const int* __restrict__ indptr,
                                                   const int* __restrict__ col_src,
                                                   const int* __restrict__ col_type,
                                                   const ushort_t* __restrict__ gat_b,
                                                   float* __restrict__ hnew3, int l) {
    __shared__ float outs[4][256];
    int n = blockIdx.x, r = blockIdx.y, g = threadIdx.x >> 6, lane = threadIdx.x & 63;
    int beg = indptr[n], end = indptr[n + 1];
    const size_t rb = (size_t)r * NN;
    float adn = a_d[(rb + n) * 4 + g];
    float eself = lrelu02(a_s[(rb + n) * 4 + g] + adn);
    float m = eself;
    for (int e = beg; e < end; ++e) {
        if (col_type[e] == r) {
            float v = lrelu02(a_s[(rb + col_src[e]) * 4 + g] + adn);
            m = fmaxf(m, v);
        }
    }
    float wself = __expf(eself - m);
    float denom = wself;
    const float* xn = xg + (rb + n) * 1024 + g * 256 + lane * 4;
    float num[4];
#pragma unroll
    for (int j = 0; j < 4; ++j) num[j] = wself * xn[j];
    for (int e = beg; e < end; ++e) {
        if (col_type[e] == r) {
            int src = col_src[e];
            float v = lrelu02(a_s[(rb + src) * 4 + g] + adn);
            float w = __expf(v - m);
            denom += w;
            const float* xs = xg + (rb + src) * 1024 + g * 256 + lane * 4;
#pragma unroll
            for (int j = 0; j < 4; ++j) num[j] += w * xs[j];
        }
    }
    float invd = 1.f / denom;
#pragma unroll
    for (int j = 0; j < 4; ++j) outs[g][lane * 4 + j] = num[j] * invd;
    __syncthreads();
    int d = threadIdx.x;
    float hv = 0.25f * (outs[0][d] + outs[1][d] + outs[2][d] + outs[3][d]) + us2f(gat_b[l * 256 + d]);
    hnew3[(rb + n) * 256 + d] = hv;
}

__global__ void update_h_kernel(float* __restrict__ h, const float* __restrict__ hnew3,
                                ushort_t* __restrict__ hb) {
    size_t i = (size_t)blockIdx.x * 256 + threadIdx.x;
    float v = fmaxf(h[i] + hnew3[i] + hnew3[(size_t)NN * 256 + i] + hnew3[(size_t)2 * NN * 256 + i], 0.f);
    h[i] = v;
    hb[i] = f2us(v);
}

__global__ __launch_bounds__(64) void final_kernel(const float* __restrict__ pos,
                                                   const ushort_t* __restrict__ log_c,
                                                   const int* __restrict__ flag,
                                                   void* __restrict__ out) {
    int n = blockIdx.x, lane = threadIdx.x;
    int bf = *flag;
    float scv = sqrtf(__expf(us2f(log_c[0])));
    f32x4 pv = *(const f32x4*)&pos[(size_t)n * 256 + lane * 4];
    float st[4]; float sq = 0.f;
#pragma unroll
    for (int j = 0; j < 4; ++j) { float t = tanhf(pv[j]) * 2.f * scv; st[j] = t; sq += t * t; }
#pragma unroll
    for (int off = 32; off > 0; off >>= 1) sq += __shfl_xor(sq, off);
    float rr = fmaxf(sqrtf(sq), 1e-8f);
    float sf = sinhf(rr) / rr;
    if (bf) {
        ushort_t* o = (ushort_t*)out;
        if (lane == 0) o[(size_t)n * 257] = f2us(coshf(rr));
#pragma unroll
        for (int j = 0; j < 4; ++j) o[(size_t)n * 257 + 1 + lane * 4 + j] = f2us(sf * st[j]);
    } else {
        float* o = (float*)out;
        if (lane == 0) o[(size_t)n * 257] = coshf(rr);
#pragma unroll
        for (int j = 0; j < 4; ++j) o[(size_t)n * 257 + 1 + lane * 4 + j] = sf * st[j];
    }
}

// ---------------------------------------------------------------------------
extern "C" void kernel_launch(void* const* d_in, const int* in_sizes, int n_in,
                              void* d_out, int out_size, void* d_ws, size_t ws_size,
                              hipStream_t stream) {
    const int* tokens = (const int*)d_in[25];
    const int* rtypes = (const int*)d_in[26];
    const int* eidx   = (const int*)d_in[27];
    const int* etype  = (const int*)d_in[28];

    char* base = (char*)d_ws;
    size_t pos = 0;
    auto alloc = [&](size_t b) -> char* {
        char* r = base + pos; pos = (pos + b + 255) & ~(size_t)255; return r;
    };

    int* flag = (int*)alloc(256);

    // ---- conversion table (weights -> canonical bf16, B^T for GEMMs)
    ConvArgs ca;
    int ne = 0; unsigned int off = 0;
    auto add = [&](const void* src, unsigned int soff, unsigned int elems,
                   int klog2, int ncol) -> unsigned int {
        ca.src[ne] = src; ca.soff[ne] = soff; ca.off[ne] = off;
        ca.nel[ne] = elems; ca.klog2[ne] = (unsigned char)klog2;
        ca.ncol[ne] = (unsigned short)ncol;
        unsigned int r = off; off += (elems + 7) & ~7u; ++ne; return r;
    };
    unsigned int oWqkv = add(d_in[1], 0, 196608, 8, 768);
                         add(d_in[1], 196608, 196608, 8, 768);
    unsigned int obqkv = add(d_in[2], 0, 1536, 0, 0);
    unsigned int oWo   = add(d_in[3], 0, 65536, 8, 256);
                         add(d_in[3], 65536, 65536, 8, 256);
    unsigned int obo   = add(d_in[4], 0, 512, 0, 0);
    unsigned int oln1g = add(d_in[5], 0, 512, 0, 0);
    unsigned int oln1b = add(d_in[6], 0, 512, 0, 0);
    unsigned int oln2g = add(d_in[7], 0, 512, 0, 0);
    unsigned int oln2b = add(d_in[8], 0, 512, 0, 0);
    unsigned int oW1   = add(d_in[9], 0, 65536, 8, 256);
                         add(d_in[9], 65536, 65536, 8, 256);
    unsigned int ob1   = add(d_in[10], 0, 512, 0, 0);
    unsigned int oW2   = add(d_in[11], 0, 65536, 8, 256);
                         add(d_in[11], 65536, 65536, 8, 256);
    unsigned int ob2   = add(d_in[12], 0, 512, 0, 0);
    unsigned int otype = add(d_in[13], 0, 2560, 0, 0);
    unsigned int omsgW = add(d_in[14], 0, 65536, 8, 256);
                         add(d_in[14], 65536, 65536, 8, 256);
                         add(d_in[14], 131072, 65536, 8, 256);
    unsigned int omsgb = add(d_in[15], 0, 768, 0, 0);
    unsigned int ogatW = add(d_in[16], 0, 262144, 8, 1024);
                         add(d_in[16], 262144, 262144, 8, 1024);
                         add(d_in[16], 524288, 262144, 8, 1024);
                         add(d_in[16], 786432, 262144, 8, 1024);
    unsigned int ogatb = add(d_in[17], 0, 1024, 0, 0);
    unsigned int oasrc = add(d_in[18], 0, 4096, 0, 0);
    unsigned int oadst = add(d_in[19], 0, 4096, 0, 0);
    unsigned int ospW1 = add(d_in[20], 0, 131072, 8, 512);
    unsigned int ospb1 = add(d_in[21], 0, 512, 0, 0);
    unsigned int ospW2 = add(d_in[22], 0, 131072, 9, 256);
    unsigned int ospb2 = add(d_in[23], 0, 256, 0, 0);
    unsigned int ologc = add(d_in[24], 0, 1, 0, 0);
    ca.off[ne] = off;
    unsigned int wtotal = off;

    // persistent allocations
    ushort_t* wtb   = (ushort_t*)alloc((size_t)wtotal * 2);
    float*    pe    = (float*)   alloc((size_t)SEQL * DIM * 4);
    float*    h     = (float*)   alloc((size_t)NN * DIM * 4);
    ushort_t* hb    = (ushort_t*)alloc((size_t)NN * DIM * 2);
    float*    a_s   = (float*)   alloc((size_t)3 * NN * 4 * 4);
    float*    a_d   = (float*)   alloc((size_t)3 * NN * 4 * 4);
    int*      counts = (int*)    alloc((size_t)NN * 4);
    int*      indptr = (int*)    alloc((size_t)(NN + 1) * 4);
    int*      cursor = (int*)    alloc((size_t)NN * 4);
    int*      col_src  = (int*)  alloc((size_t)EDGES * 4);
    int*      col_type = (int*)  alloc((size_t)EDGES * 4);

    // phase-shared scratch
    size_t spos0 = pos;
    ushort_t* Xc  = (ushort_t*)alloc((size_t)CROWS * DIM * 2);   // 32 MB
    ushort_t* QKV = (ushort_t*)alloc((size_t)CROWS * 768 * 2);   // 96 MB
    ushort_t* Oc  = (ushort_t*)alloc((size_t)CROWS * DIM * 2);   // 32 MB
    pos = spos0;                                                  // overlap phase 2
    ushort_t* th    = (ushort_t*)alloc((size_t)NN * 768 * 2);
    float*    xg    = (float*)   alloc((size_t)3 * NN * 1024 * 4);
    float*    hnew3 = (float*)   alloc((size_t)3 * NN * DIM * 4);
    ushort_t* thead = (ushort_t*)alloc((size_t)NN * 512 * 2);
    float*    posb  = (float*)   alloc((size_t)NN * DIM * 4);

    const ushort_t* WqkvT = wtb + oWqkv;
    const ushort_t* bqkv  = wtb + obqkv;
    const ushort_t* WoT   = wtb + oWo;
    const ushort_t* bo    = wtb + obo;
    const ushort_t* ln1g  = wtb + oln1g;
    const ushort_t* ln1b  = wtb + oln1b;
    const ushort_t* ln2g  = wtb + oln2g;
    const ushort_t* ln2b  = wtb + oln2b;
    const ushort_t* W1T   = wtb + oW1;
    const ushort_t* b1    = wtb + ob1;
    const ushort_t* W2T   = wtb + oW2;
    const ushort_t* b2    = wtb + ob2;
    const ushort_t* type_emb = wtb + otype;
    const ushort_t* msgWT = wtb + omsgW;
    const ushort_t* msg_b = wtb + omsgb;
    const ushort_t* gatWT = wtb + ogatW;
    const ushort_t* gat_b = wtb + ogatb;
    const ushort_t* gasrc = wtb + oasrc;
    const ushort_t* gadst = wtb + oadst;
    const ushort_t* spW1T = wtb + ospW1;
    const ushort_t* spb1  = wtb + ospb1;
    const ushort_t* spW2T = wtb + ospW2;
    const ushort_t* spb2  = wtb + ospb2;
    const ushort_t* log_c = wtb + ologc;

    sniff_kernel<<<1, 256, 0, stream>>>((const unsigned int*)d_in[1], flag);
    convert_kernel<<<2048, 256, 0, stream>>>(ca, flag, wtb, wtotal);

    pe_kernel<<<SEQL, DIM, 0, stream>>>(pe);
    hipMemsetAsync(counts, 0, NN * 4, stream);
    hist_kernel<<<EDGES / 256, 256, 0, stream>>>(eidx, counts);
    scan_kernel<<<1, 256, 0, stream>>>(counts, indptr, cursor);
    scatter_kernel<<<EDGES / 256, 256, 0, stream>>>(eidx, etype, cursor, col_src, col_type);

    for (int c = 0; c < CHUNKS; ++c) {
        int row0 = c * CROWS;
        embed_kernel<<<CROWS, DIM, 0, stream>>>(d_in[0], flag, tokens, pe, Xc, row0);
        for (int l = 0; l < 2; ++l) {
            gemm_bt<false, true><<<dim3(CROWS / 128, 6), 256, 0, stream>>>(
                Xc, WqkvT + (size_t)l * 196608, bqkv + l * 768, QKV, CROWS, 768, DIM, DIM, 0, 0);
            attn_mfma<<<dim3(CN, 4), 128, 0, stream>>>(QKV, Oc);
            gemm_ln<<<CROWS / 128, 512, 0, stream>>>(
                Oc, WoT + (size_t)l * 65536, bo + l * DIM, Xc, ln1g + l * DIM, ln1b + l * DIM, DIM);
            gemm_bt<true, true><<<dim3(CROWS / 128, 2), 256, 0, stream>>>(
                Xc, W1T + (size_t)l * 65536, b1 + l * DIM, Oc, CROWS, DIM, DIM, DIM, 0, 0);
            gemm_ln<<<CROWS / 128, 512, 0, stream>>>(
                Oc, W2T + (size_t)l * 65536, b2 + l * DIM, Xc, ln2g + l * DIM, ln2b + l * DIM, DIM);
        }
        mean_kernel<<<CN, DIM, 0, stream>>>(Xc, type_emb, rtypes, h, hb, c * CN);
    }

    for (int l = 0; l < 4; ++l) {
        gemm_bt<false, true><<<dim3(NN / 128, 6), 256, 0, stream>>>(
            hb, msgWT, msg_b, th, NN, 768, DIM, DIM, 0, 0);
        gemm_bt<false, false><<<dim3(NN / 128, 8, 3), 256, 0, stream>>>(
            th, gatWT + (size_t)l * 262144, nullptr, xg, NN, 1024, DIM, 768,
            (size_t)256, (size_t)NN * 1024);
        asad_kernel<<<dim3(NN, 3), 256, 0, stream>>>(xg, gasrc, gadst, a_s, a_d, l);
        edge_kernel<<<dim3(NN, 3), 256, 0, stream>>>(xg, a_s, a_d, indptr, col_src, col_type,
                                                     gat_b, hnew3, l);
        update_h_kernel<<<NN, 256, 0, stream>>>(h, hnew3, hb);
    }

    gemm_bt<true, true><<<dim3(NN / 128, 4), 256, 0, stream>>>(
        hb, spW1T, spb1, thead, NN, 512, DIM, DIM, 0, 0);
    gemm_bt<false, false><<<dim3(NN / 128, 2), 256, 0, stream>>>(
        thead, spW2T, spb2, posb, NN, DIM, 512, 512, 0, 0);
    final_kernel<<<NN, 64, 0, stream>>>(posb, log_c, flag, d_out);
}

// Round 5
// 1192.415 us; speedup vs baseline: 2.3844x; 1.0601x over previous
//
#include <hip/hip_runtime.h>
#include <hip/hip_bf16.h>

#define NN 2048
#define SEQL 64
#define DIM 256
#define NHEAD 8
#define EDGES 32768
#define CHUNKS 2
#define CN (NN / CHUNKS)          // 1024 nodes per chunk
#define CROWS (CN * SEQL)         // 65536 rows per chunk

typedef __attribute__((ext_vector_type(8))) short short8;
typedef __attribute__((ext_vector_type(4))) float f32x4;
typedef __attribute__((ext_vector_type(4))) unsigned short us4;
typedef unsigned short ushort_t;

__device__ __forceinline__ float us2f(unsigned short u) {
    union { unsigned int i; float f; } x; x.i = ((unsigned int)u) << 16; return x.f;
}
__device__ __forceinline__ unsigned short f2us(float f) {
    union { float f; unsigned int i; } u; u.f = f;
    unsigned int r = u.i + 0x7fffu + ((u.i >> 16) & 1u);
    return (unsigned short)(r >> 16);
}
__device__ __forceinline__ float lrelu02(float v) { return v < 0.f ? 0.2f * v : v; }

// async global->LDS, 16B per lane; LDS dest must be wave-uniform base
__device__ __forceinline__ void gload_lds16(const void* g, void* l) {
    __builtin_amdgcn_global_load_lds(
        (const __attribute__((address_space(1))) unsigned int*)g,
        (__attribute__((address_space(3))) unsigned int*)l, 16, 0, 0);
}

// ---------------------------------------------------------------------------
// dtype sniff (bf16-packed vs f32 inputs)
// ---------------------------------------------------------------------------
__global__ void sniff_kernel(const unsigned int* __restrict__ w, int* __restrict__ flag) {
    __shared__ int cnt;
    if (threadIdx.x == 0) cnt = 0;
    __syncthreads();
    unsigned int v = w[(size_t)threadIdx.x * 509];
    unsigned int e_lo = (v >> 7) & 0xffu;
    if (e_lo >= 0x6eu && e_lo <= 0x7fu) atomicAdd(&cnt, 1);
    __syncthreads();
    if (threadIdx.x == 0) *flag = (cnt > 128) ? 1 : 0;   // 1 = inputs are bf16
}

// ---------------------------------------------------------------------------
// Weight canonicalization to bf16, with optional per-slice transpose
// ---------------------------------------------------------------------------
#define NE 33
struct ConvArgs {
    const void* src[NE];
    unsigned int soff[NE];
    unsigned int off[NE + 1];
    unsigned int nel[NE];
    unsigned short ncol[NE];
    unsigned char klog2[NE];
};

__global__ void convert_kernel(ConvArgs a, const int* __restrict__ flag,
                               ushort_t* __restrict__ dst, unsigned int total) {
    const int bf = *flag;
    for (unsigned int i = blockIdx.x * 256 + threadIdx.x; i < total; i += gridDim.x * 256) {
        int e = 0;
        while (a.off[e + 1] <= i) ++e;
        unsigned int j = i - a.off[e];
        ushort_t v = 0;
        if (j < a.nel[e]) {
            unsigned int sidx;
            if (a.klog2[e]) {
                unsigned int K = 1u << a.klog2[e];
                unsigned int k = j & (K - 1), n = j >> a.klog2[e];
                sidx = k * (unsigned int)a.ncol[e] + n;
            } else sidx = j;
            sidx += a.soff[e];
            if (bf) v = ((const ushort_t*)a.src[e])[sidx];
            else    v = f2us(((const float*)a.src[e])[sidx]);
        }
        dst[i] = v;
    }
}

// ---------------------------------------------------------------------------
// bf16 MFMA GEMM, pre-transposed B, double-buffered prefetch staging with
// source-side chunk swizzle (chunk ^= (row>>1)&3 kills the 8-way conflict).
// C[z][M,N] = A[z][M,K] @ BT[N,K]^T (+bias)(+relu)
// ---------------------------------------------------------------------------
template <bool RELU, bool OUT_BF16>
__global__ __launch_bounds__(256) void gemm_bt(
    const ushort_t* __restrict__ A, const ushort_t* __restrict__ BT,
    const ushort_t* __restrict__ bias, void* __restrict__ C,
    int M, int N, int K, int lda, size_t a_off_z, size_t c_off_z)
{
    __shared__ __align__(16) short a_lds[2][128][32];
    __shared__ __align__(16) short b_lds[2][128][32];

    const int tid  = threadIdx.x;
    const int lane = tid & 63;
    const int wave = tid >> 6;
    const int wr = wave >> 1, wc = wave & 1;
    const size_t mbase = (size_t)blockIdx.x * 128;
    const size_t nbase = (size_t)blockIdx.y * 128;
    A += (size_t)blockIdx.z * a_off_z;
    const size_t czoff = (size_t)blockIdx.z * c_off_z;

    f32x4 acc[4][4];
    const f32x4 fzero = {0.f, 0.f, 0.f, 0.f};
#pragma unroll
    for (int i = 0; i < 4; ++i)
#pragma unroll
        for (int j = 0; j < 4; ++j) acc[i][j] = fzero;

    const int srow = tid >> 2;          // 0..63
    const int ksw0 = (((tid & 3) ^ ((srow >> 1) & 3)) * 8);   // swizzled chunk
    const int rl = lane & 15;
    // read-side swizzled k-offset (logical chunk lane>>4, same row-XOR)
    const int kfs = (((lane >> 4) ^ ((rl >> 1) & 3)) * 8);

    const int nk = K >> 5;
    auto stage = [&](int buf, int k0) {
        short* lA = &a_lds[buf][0][0] + wave * 512;
        short* lB = &b_lds[buf][0][0] + wave * 512;
        gload_lds16(A  + (mbase + srow)      * (size_t)lda + k0 + ksw0, lA);
        gload_lds16(A  + (mbase + srow + 64) * (size_t)lda + k0 + ksw0, lA + 2048);
        gload_lds16(BT + (nbase + srow)      * (size_t)K   + k0 + ksw0, lB);
        gload_lds16(BT + (nbase + srow + 64) * (size_t)K   + k0 + ksw0, lB + 2048);
    };

    stage(0, 0);
    __syncthreads();
    for (int t = 0; t < nk; ++t) {
        const int cur = t & 1;
        if (t + 1 < nk) stage(cur ^ 1, (t + 1) * 32);

        short8 af[4], bfr[4];
#pragma unroll
        for (int m = 0; m < 4; ++m) af[m]  = *(const short8*)&a_lds[cur][wr * 64 + m * 16 + rl][kfs];
#pragma unroll
        for (int n = 0; n < 4; ++n) bfr[n] = *(const short8*)&b_lds[cur][wc * 64 + n * 16 + rl][kfs];
#pragma unroll
        for (int m = 0; m < 4; ++m)
#pragma unroll
            for (int n = 0; n < 4; ++n)
                acc[m][n] = __builtin_amdgcn_mfma_f32_16x16x32_bf16(af[m], bfr[n], acc[m][n], 0, 0, 0);
        if (t + 1 < nk) __syncthreads();
    }

    const int rq = (lane >> 4) * 4;
#pragma unroll
    for (int m = 0; m < 4; ++m) {
#pragma unroll
        for (int n = 0; n < 4; ++n) {
            size_t gcol = nbase + wc * 64 + n * 16 + rl;
            float bv = bias ? us2f(bias[gcol]) : 0.f;
#pragma unroll
            for (int q = 0; q < 4; ++q) {
                size_t grow = mbase + wr * 64 + m * 16 + rq + q;
                float v = acc[m][n][q] + bv;
                if (RELU) v = fmaxf(v, 0.f);
                if (OUT_BF16) ((ushort_t*)C)[czoff + grow * N + gcol] = f2us(v);
                else          ((float*)C)[czoff + grow * N + gcol] = v;
            }
        }
    }
}

// ---------------------------------------------------------------------------
// Fused GEMM + residual + LayerNorm (N=256): X = LN(X + A@BT^T + bias)*g + b
// tile 128x256, 512 threads (8 waves 2x4), dbuf prefetch + swizzle
// ---------------------------------------------------------------------------
__global__ __launch_bounds__(512) void gemm_ln(
    const ushort_t* __restrict__ A, const ushort_t* __restrict__ BT,
    const ushort_t* __restrict__ bias, ushort_t* __restrict__ X,
    const ushort_t* __restrict__ gg, const ushort_t* __restrict__ bb, int K)
{
    __shared__ __align__(16) short a_lds[2][128][32];
    __shared__ __align__(16) short b_lds[2][256][32];
    __shared__ float st_part[128][8];
    __shared__ float st_fin[128][2];

    const int tid  = threadIdx.x;
    const int lane = tid & 63;
    const int wave = tid >> 6;
    const int wr = wave >> 2, wc = wave & 3;
    const size_t mbase = (size_t)blockIdx.x * 128;

    f32x4 acc[4][4];
    const f32x4 fzero = {0.f, 0.f, 0.f, 0.f};
#pragma unroll
    for (int i = 0; i < 4; ++i)
#pragma unroll
        for (int j = 0; j < 4; ++j) acc[i][j] = fzero;

    const int srow = tid >> 2;          // 0..127
    const int ksw0 = (((tid & 3) ^ ((srow >> 1) & 3)) * 8);
    const int rl = lane & 15;
    const int g  = lane >> 4;
    const int kfs = ((g ^ ((rl >> 1) & 3)) * 8);

    const int nk = K >> 5;
    auto stage = [&](int buf, int k0) {
        gload_lds16(A  + (mbase + srow) * (size_t)K + k0 + ksw0,
                    &a_lds[buf][0][0] + wave * 512);
        gload_lds16(BT + (size_t)srow         * K + k0 + ksw0,
                    &b_lds[buf][0][0] + wave * 512);
        gload_lds16(BT + (size_t)(srow + 128) * K + k0 + ksw0,
                    &b_lds[buf][0][0] + wave * 512 + 4096);
    };

    stage(0, 0);
    __syncthreads();
    for (int t = 0; t < nk; ++t) {
        const int cur = t & 1;
        if (t + 1 < nk) stage(cur ^ 1, (t + 1) * 32);

        short8 af[4], bfr[4];
#pragma unroll
        for (int m = 0; m < 4; ++m) af[m]  = *(const short8*)&a_lds[cur][wr * 64 + m * 16 + rl][kfs];
#pragma unroll
        for (int n = 0; n < 4; ++n) bfr[n] = *(const short8*)&b_lds[cur][wc * 64 + n * 16 + rl][kfs];
#pragma unroll
        for (int m = 0; m < 4; ++m)
#pragma unroll
            for (int n = 0; n < 4; ++n)
                acc[m][n] = __builtin_amdgcn_mfma_f32_16x16x32_bf16(af[m], bfr[n], acc[m][n], 0, 0, 0);
        if (t + 1 < nk) __syncthreads();
    }

#pragma unroll
    for (int m = 0; m < 4; ++m)
#pragma unroll
        for (int n = 0; n < 4; ++n) {
            int gcol = wc * 64 + n * 16 + rl;
            float bv = us2f(bias[gcol]);
#pragma unroll
            for (int r = 0; r < 4; ++r) {
                size_t grow = mbase + wr * 64 + m * 16 + g * 4 + r;
                acc[m][n][r] += bv + us2f(X[grow * 256 + gcol]);
            }
        }
#pragma unroll
    for (int m = 0; m < 4; ++m)
#pragma unroll
        for (int r = 0; r < 4; ++r) {
            float ps = 0.f, pq = 0.f;
#pragma unroll
            for (int n = 0; n < 4; ++n) { float v = acc[m][n][r]; ps += v; pq += v * v; }
#pragma unroll
            for (int off = 1; off < 16; off <<= 1) { ps += __shfl_xor(ps, off); pq += __shfl_xor(pq, off); }
            if (rl == 0) {
                int row = wr * 64 + m * 16 + g * 4 + r;
                st_part[row][wc] = ps;
                st_part[row][4 + wc] = pq;
            }
        }
    __syncthreads();
    if (tid < 128) {
        float s = st_part[tid][0] + st_part[tid][1] + st_part[tid][2] + st_part[tid][3];
        float q = st_part[tid][4] + st_part[tid][5] + st_part[tid][6] + st_part[tid][7];
        float mean = s * (1.f / 256.f);
        float var = q * (1.f / 256.f) - mean * mean;
        st_fin[tid][0] = mean;
        st_fin[tid][1] = rsqrtf(var + 1e-5f);
    }
    __syncthreads();
#pragma unroll
    for (int m = 0; m < 4; ++m)
#pragma unroll
        for (int n = 0; n < 4; ++n) {
            int gcol = wc * 64 + n * 16 + rl;
            float gv = us2f(gg[gcol]), bv = us2f(bb[gcol]);
#pragma unroll
            for (int r = 0; r < 4; ++r) {
                int row = wr * 64 + m * 16 + g * 4 + r;
                float out = (acc[m][n][r] - st_fin[row][0]) * st_fin[row][1] * gv + bv;
                X[(mbase + row) * 256 + gcol] = f2us(out);
            }
        }
}

// ---------------------------------------------------------------------------
// MFMA attention: 1 wave per (node, head); 2 waves per block.
// ---------------------------------------------------------------------------
__global__ __launch_bounds__(128) void attn_mfma(const ushort_t* __restrict__ qkv,
                                                 ushort_t* __restrict__ O) {
    __shared__ ushort_t smem[2][6912];
    const int w = threadIdx.x >> 6, lane = threadIdx.x & 63;
    const int h = blockIdx.y * 2 + w;
    const int rl = lane & 15, g = lane >> 4;
    const size_t rowbase = (size_t)blockIdx.x * 64;
    ushort_t* vt = smem[w];
    ushort_t* pl = smem[w] + 2304;

    const ushort_t* vp = qkv + (rowbase + lane) * 768 + 512 + h * 32;
#pragma unroll
    for (int i = 0; i < 4; ++i) {
        union { short8 v; ushort_t s[8]; } u;
        u.v = *(const short8*)(vp + i * 8);
#pragma unroll
        for (int j = 0; j < 8; ++j) vt[(i * 8 + j) * 72 + lane] = u.s[j];
    }

    short8 kf[4], qf[4];
#pragma unroll
    for (int t = 0; t < 4; ++t) {
        kf[t] = *(const short8*)(qkv + (rowbase + t * 16 + rl) * 768 + 256 + h * 32 + g * 8);
        qf[t] = *(const short8*)(qkv + (rowbase + t * 16 + rl) * 768 +       h * 32 + g * 8);
    }

    f32x4 s[4][4];
    const f32x4 fzero = {0.f, 0.f, 0.f, 0.f};
#pragma unroll
    for (int kt = 0; kt < 4; ++kt)
#pragma unroll
        for (int qt = 0; qt < 4; ++qt) s[kt][qt] = fzero;
#pragma unroll
    for (int kt = 0; kt < 4; ++kt)
#pragma unroll
        for (int qt = 0; qt < 4; ++qt)
            s[kt][qt] = __builtin_amdgcn_mfma_f32_16x16x32_bf16(kf[kt], qf[qt], s[kt][qt], 0, 0, 0);

    const float sc = 0.17677669529663687f;
    float inv[4];
#pragma unroll
    for (int qt = 0; qt < 4; ++qt) {
        float m = -1e30f;
#pragma unroll
        for (int kt = 0; kt < 4; ++kt)
#pragma unroll
            for (int r = 0; r < 4; ++r) { s[kt][qt][r] *= sc; m = fmaxf(m, s[kt][qt][r]); }
        m = fmaxf(m, __shfl_xor(m, 16));
        m = fmaxf(m, __shfl_xor(m, 32));
        float sum = 0.f;
#pragma unroll
        for (int kt = 0; kt < 4; ++kt)
#pragma unroll
            for (int r = 0; r < 4; ++r) { float e = __expf(s[kt][qt][r] - m); s[kt][qt][r] = e; sum += e; }
        sum += __shfl_xor(sum, 16);
        sum += __shfl_xor(sum, 32);
        inv[qt] = 1.f / sum;
    }

#pragma unroll
    for (int qt = 0; qt < 4; ++qt)
#pragma unroll
        for (int kt = 0; kt < 4; ++kt) {
            us4 pk;
#pragma unroll
            for (int r = 0; r < 4; ++r) pk[r] = f2us(s[kt][qt][r] * inv[qt]);
            *(us4*)&pl[(qt * 16 + rl) * 72 + kt * 16 + g * 4] = pk;
        }
    asm volatile("s_waitcnt lgkmcnt(0)" ::: "memory");
    __builtin_amdgcn_sched_barrier(0);

    f32x4 o[2][4];
#pragma unroll
    for (int dt = 0; dt < 2; ++dt)
#pragma unroll
        for (int qt = 0; qt < 4; ++qt) o[dt][qt] = fzero;
#pragma unroll
    for (int ks = 0; ks < 2; ++ks) {
        short8 va[2];
#pragma unroll
        for (int dt = 0; dt < 2; ++dt)
            va[dt] = *(const short8*)&vt[(dt * 16 + rl) * 72 + ks * 32 + g * 8];
#pragma unroll
        for (int qt = 0; qt < 4; ++qt) {
            short8 pb = *(const short8*)&pl[(qt * 16 + rl) * 72 + ks * 32 + g * 8];
#pragma unroll
            for (int dt = 0; dt < 2; ++dt)
                o[dt][qt] = __builtin_amdgcn_mfma_f32_16x16x32_bf16(va[dt], pb, o[dt][qt], 0, 0, 0);
        }
    }

#pragma unroll
    for (int dt = 0; dt < 2; ++dt)
#pragma unroll
        for (int qt = 0; qt < 4; ++qt) {
            us4 ov;
#pragma unroll
            for (int r = 0; r < 4; ++r) ov[r] = f2us(o[dt][qt][r]);
            *(us4*)&pl[(qt * 16 + rl) * 40 + dt * 16 + g * 4] = ov;
        }
    asm volatile("s_waitcnt lgkmcnt(0)" ::: "memory");
    __builtin_amdgcn_sched_barrier(0);
    ushort_t* op = O + (rowbase + lane) * 256 + h * 32;
#pragma unroll
    for (int t = 0; t < 4; ++t)
        *(short8*)(op + t * 8) = *(const short8*)&pl[lane * 40 + t * 8];
}

// ---------------------------------------------------------------------------
__global__ void pe_kernel(float* __restrict__ pe) {
    int s = blockIdx.x, d = threadIdx.x;
    int i = d >> 1;
    float freq = __expf((float)(2 * i) * (-9.210340371976184f / 256.f));
    float ang = (float)s * freq;
    pe[s * DIM + d] = (d & 1) ? cosf(ang) : sinf(ang);
}

// vectorized x4: 64 threads per row
__global__ __launch_bounds__(64) void embed_kernel(const void* __restrict__ tok_emb,
                                                   const int* __restrict__ flag,
                                                   const int* __restrict__ tokens,
                                                   const float* __restrict__ pe,
                                                   ushort_t* __restrict__ X, int row0) {
    int lr = blockIdx.x, t = threadIdx.x;
    int grow = row0 + lr;
    int tok = tokens[grow];
    int s = grow & 63;
    int d0 = t * 4;
    size_t idx = (size_t)tok * DIM + d0;
    f32x4 pv = *(const f32x4*)&pe[s * DIM + d0];
    us4 out;
    if (*flag) {
        us4 tv = *(const us4*)((const ushort_t*)tok_emb + idx);
#pragma unroll
        for (int j = 0; j < 4; ++j) out[j] = f2us(us2f(tv[j]) * 16.f + pv[j]);
    } else {
        f32x4 tv = *(const f32x4*)((const float*)tok_emb + idx);
#pragma unroll
        for (int j = 0; j < 4; ++j) out[j] = f2us(tv[j] * 16.f + pv[j]);
    }
    *(us4*)&X[(size_t)lr * DIM + d0] = out;
}

__global__ void mean_kernel(const ushort_t* __restrict__ Xc,
                            const ushort_t* __restrict__ type_emb,
                            const int* __restrict__ rtypes,
                            float* __restrict__ h, ushort_t* __restrict__ hb, int n0) {
    int nl = blockIdx.x, d = threadIdx.x;
    float acc = 0.f;
    for (int s = 0; s < 64; ++s) acc += us2f(Xc[((size_t)nl * 64 + s) * DIM + d]);
    int n = n0 + nl;
    float val = acc * (1.f / 64.f) + us2f(type_emb[(size_t)rtypes[n] * DIM + d]);
    h[(size_t)n * DIM + d] = val;
    hb[(size_t)n * DIM + d] = f2us(val);
}

// ---------------------------------------------------------------------------
// CSR build (by dst)
// ---------------------------------------------------------------------------
__global__ void hist_kernel(const int* __restrict__ ei, int* __restrict__ counts) {
    int e = blockIdx.x * 256 + threadIdx.x;
    if (e < EDGES) atomicAdd(&counts[ei[EDGES + e]], 1);
}
__global__ __launch_bounds__(256) void scan_kernel(const int* __restrict__ counts,
                                                   int* __restrict__ indptr,
                                                   int* __restrict__ cursor) {
    __shared__ int part[256];
    int t = threadIdx.x;
    int local[8]; int s = 0;
#pragma unroll
    for (int i = 0; i < 8; ++i) { local[i] = s; s += counts[t * 8 + i]; }
    part[t] = s;
    __syncthreads();
    for (int d = 1; d < 256; d <<= 1) {
        int val = (t >= d) ? part[t - d] : 0;
        __syncthreads();
        part[t] += val;
        __syncthreads();
    }
    int base = part[t] - s;
#pragma unroll
    for (int i = 0; i < 8; ++i) { int v = base + local[i]; indptr[t * 8 + i] = v; cursor[t * 8 + i] = v; }
    if (t == 255) indptr[NN] = part[255];
}
__global__ void scatter_kernel(const int* __restrict__ ei, const int* __restrict__ et,
                               int* __restrict__ cursor, int* __restrict__ col_src,
                               int* __restrict__ col_type) {
    int e = blockIdx.x * 256 + threadIdx.x;
    if (e < EDGES) {
        int d = ei[EDGES + e];
        int pp = atomicAdd(&cursor[d], 1);
        col_src[pp] = ei[e];
        col_type[pp] = et[e];
    }
}

// a_s/a_d: grid (NN, 3), block 256 = 4 head-waves
__global__ __launch_bounds__(256) void asad_kernel(const float* __restrict__ xg,
                                                   const ushort_t* __restrict__ asrc,
                                                   const ushort_t* __restrict__ adst,
                                                   float* __restrict__ a_s, float* __restrict__ a_d,
                                                   int l) {
    int n = blockIdx.x, r = blockIdx.y, g = threadIdx.x >> 6, lane = threadIdx.x & 63;
    const float* xp = xg + ((size_t)r * NN + n) * 1024 + g * 256 + lane * 4;
    const ushort_t* sp = asrc + ((size_t)l * 4 + g) * 256 + lane * 4;
    const ushort_t* dp = adst + ((size_t)l * 4 + g) * 256 + lane * 4;
    float ss = 0.f, dd = 0.f;
#pragma unroll
    for (int j = 0; j < 4; ++j) { float x = xp[j]; ss += x * us2f(sp[j]); dd += x * us2f(dp[j]); }
#pragma unroll
    for (int off = 32; off > 0; off >>= 1) { ss += __shfl_xor(ss, off); dd += __shfl_xor(dd, off); }
    if (lane == 0) {
        a_s[((size_t)r * NN + n) * 4 + g] = ss;
        a_d[((size_t)r * NN + n) * 4 + g] = dd;
    }
}

// GAT edge-softmax + aggregate: grid (NN, 3); writes hnew3[r] (no memset)
__global__ __launch_bounds__(256) void edge_kernel(const float* __restrict__ xg,
                                                   const float* __restrict__ a_s,
                                                   const float* __restrict__ a_d,
                                                   const int* __restrict__ indptr,
                                                   const int* __restrict__ col_src,
                                                   const int* __restrict__ col_type,
                                                   const ushort_t* __restrict__ gat_b,
                                                   float* __restrict__ hnew3, int l) {
    __shared__ float outs[4][256];
    int n = blockIdx.x, r = blockIdx.y, g = threadIdx.x >> 6, lane = threadIdx.x & 63;
    int beg = indptr[n], end = indptr[n + 1];
    const size_t rb = (size_t)r * NN;
    float adn = a_d[(rb + n) * 4 + g];
    float eself = lrelu02(a_s[(rb + n) * 4 + g] + adn);
    float m = eself;
    for (int e = beg; e < end; ++e) {
        if (col_type[e] == r) {
            float v = lrelu02(a_s[(rb + col_src[e]) * 4 + g] + adn);
            m = fmaxf(m, v);
        }
    }
    float wself = __expf(eself - m);
    float denom = wself;
    const float* xn = xg + (rb + n) * 1024 + g * 256 + lane * 4;
    float num[4];
#pragma unroll
    for (int j = 0; j < 4; ++j) num[j] = wself * xn[j];
    for (int e = beg; e < end; ++e) {
        if (col_type[e] == r) {
            int src = col_src[e];
            float v = lrelu02(a_s[(rb + src) * 4 + g] + adn);
            float w = __expf(v - m);
            denom += w;
            const float* xs = xg + (rb + src) * 1024 + g * 256 + lane * 4;
#pragma unroll
            for (int j = 0; j < 4; ++j) num[j] += w * xs[j];
        }
    }
    float invd = 1.f / denom;
#pragma unroll
    for (int j = 0; j < 4; ++j) outs[g][lane * 4 + j] = num[j] * invd;
    __syncthreads();
    int d = threadIdx.x;
    float hv = 0.25f * (outs[0][d] + outs[1][d] + outs[2][d] + outs[3][d]) + us2f(gat_b[l * 256 + d]);
    hnew3[(rb + n) * 256 + d] = hv;
}

__global__ void update_h_kernel(float* __restrict__ h, const float* __restrict__ hnew3,
                                ushort_t* __restrict__ hb) {
    size_t i = (size_t)blockIdx.x * 256 + threadIdx.x;
    float v = fmaxf(h[i] + hnew3[i] + hnew3[(size_t)NN * 256 + i] + hnew3[(size_t)2 * NN * 256 + i], 0.f);
    h[i] = v;
    hb[i] = f2us(v);
}

__global__ __launch_bounds__(64) void final_kernel(const float* __restrict__ pos,
                                                   const ushort_t* __restrict__ log_c,
                                                   const int* __restrict__ flag,
                                                   void* __restrict__ out) {
    int n = blockIdx.x, lane = threadIdx.x;
    int bf = *flag;
    float scv = sqrtf(__expf(us2f(log_c[0])));
    f32x4 pv = *(const f32x4*)&pos[(size_t)n * 256 + lane * 4];
    float st[4]; float sq = 0.f;
#pragma unroll
    for (int j = 0; j < 4; ++j) { float t = tanhf(pv[j]) * 2.f * scv; st[j] = t; sq += t * t; }
#pragma unroll
    for (int off = 32; off > 0; off >>= 1) sq += __shfl_xor(sq, off);
    float rr = fmaxf(sqrtf(sq), 1e-8f);
    float sf = sinhf(rr) / rr;
    if (bf) {
        ushort_t* o = (ushort_t*)out;
        if (lane == 0) o[(size_t)n * 257] = f2us(coshf(rr));
#pragma unroll
        for (int j = 0; j < 4; ++j) o[(size_t)n * 257 + 1 + lane * 4 + j] = f2us(sf * st[j]);
    } else {
        float* o = (float*)out;
        if (lane == 0) o[(size_t)n * 257] = coshf(rr);
#pragma unroll
        for (int j = 0; j < 4; ++j) o[(size_t)n * 257 + 1 + lane * 4 + j] = sf * st[j];
    }
}

// ---------------------------------------------------------------------------
extern "C" void kernel_launch(void* const* d_in, const int* in_sizes, int n_in,
                              void* d_out, int out_size, void* d_ws, size_t ws_size,
                              hipStream_t stream) {
    const int* tokens = (const int*)d_in[25];
    const int* rtypes = (const int*)d_in[26];
    const int* eidx   = (const int*)d_in[27];
    const int* etype  = (const int*)d_in[28];

    char* base = (char*)d_ws;
    size_t pos = 0;
    auto alloc = [&](size_t b) -> char* {
        char* r = base + pos; pos = (pos + b + 255) & ~(size_t)255; return r;
    };

    int* flag = (int*)alloc(256);

    // ---- conversion table (weights -> canonical bf16, B^T for GEMMs)
    ConvArgs ca;
    int ne = 0; unsigned int off = 0;
    auto add = [&](const void* src, unsigned int soff, unsigned int elems,
                   int klog2, int ncol) -> unsigned int {
        ca.src[ne] = src; ca.soff[ne] = soff; ca.off[ne] = off;
        ca.nel[ne] = elems; ca.klog2[ne] = (unsigned char)klog2;
        ca.ncol[ne] = (unsigned short)ncol;
        unsigned int r = off; off += (elems + 7) & ~7u; ++ne; return r;
    };
    unsigned int oWqkv = add(d_in[1], 0, 196608, 8, 768);
                         add(d_in[1], 196608, 196608, 8, 768);
    unsigned int obqkv = add(d_in[2], 0, 1536, 0, 0);
    unsigned int oWo   = add(d_in[3], 0, 65536, 8, 256);
                         add(d_in[3], 65536, 65536, 8, 256);
    unsigned int obo   = add(d_in[4], 0, 512, 0, 0);
    unsigned int oln1g = add(d_in[5], 0, 512, 0, 0);
    unsigned int oln1b = add(d_in[6], 0, 512, 0, 0);
    unsigned int oln2g = add(d_in[7], 0, 512, 0, 0);
    unsigned int oln2b = add(d_in[8], 0, 512, 0, 0);
    unsigned int oW1   = add(d_in[9], 0, 65536, 8, 256);
                         add(d_in[9], 65536, 65536, 8, 256);
    unsigned int ob1   = add(d_in[10], 0, 512, 0, 0);
    unsigned int oW2   = add(d_in[11], 0, 65536, 8, 256);
                         add(d_in[11], 65536, 65536, 8, 256);
    unsigned int ob2   = add(d_in[12], 0, 512, 0, 0);
    unsigned int otype = add(d_in[13], 0, 2560, 0, 0);
    unsigned int omsgW = add(d_in[14], 0, 65536, 8, 256);
                         add(d_in[14], 65536, 65536, 8, 256);
                         add(d_in[14], 131072, 65536, 8, 256);
    unsigned int omsgb = add(d_in[15], 0, 768, 0, 0);
    unsigned int ogatW = add(d_in[16], 0, 262144, 8, 1024);
                         add(d_in[16], 262144, 262144, 8, 1024);
                         add(d_in[16], 524288, 262144, 8, 1024);
                         add(d_in[16], 786432, 262144, 8, 1024);
    unsigned int ogatb = add(d_in[17], 0, 1024, 0, 0);
    unsigned int oasrc = add(d_in[18], 0, 4096, 0, 0);
    unsigned int oadst = add(d_in[19], 0, 4096, 0, 0);
    unsigned int ospW1 = add(d_in[20], 0, 131072, 8, 512);
    unsigned int ospb1 = add(d_in[21], 0, 512, 0, 0);
    unsigned int ospW2 = add(d_in[22], 0, 131072, 9, 256);
    unsigned int ospb2 = add(d_in[23], 0, 256, 0, 0);
    unsigned int ologc = add(d_in[24], 0, 1, 0, 0);
    ca.off[ne] = off;
    unsigned int wtotal = off;

    // persistent allocations
    ushort_t* wtb   = (ushort_t*)alloc((size_t)wtotal * 2);
    float*    pe    = (float*)   alloc((size_t)SEQL * DIM * 4);
    float*    h     = (float*)   alloc((size_t)NN * DIM * 4);
    ushort_t* hb    = (ushort_t*)alloc((size_t)NN * DIM * 2);
    float*    a_s   = (float*)   alloc((size_t)3 * NN * 4 * 4);
    float*    a_d   = (float*)   alloc((size_t)3 * NN * 4 * 4);
    int*      counts = (int*)    alloc((size_t)NN * 4);
    int*      indptr = (int*)    alloc((size_t)(NN + 1) * 4);
    int*      cursor = (int*)    alloc((size_t)NN * 4);
    int*      col_src  = (int*)  alloc((size_t)EDGES * 4);
    int*      col_type = (int*)  alloc((size_t)EDGES * 4);

    // phase-shared scratch
    size_t spos0 = pos;
    ushort_t* Xc  = (ushort_t*)alloc((size_t)CROWS * DIM * 2);   // 32 MB
    ushort_t* QKV = (ushort_t*)alloc((size_t)CROWS * 768 * 2);   // 96 MB
    ushort_t* Oc  = (ushort_t*)alloc((size_t)CROWS * DIM * 2);   // 32 MB
    pos = spos0;                                                  // overlap phase 2
    ushort_t* th    = (ushort_t*)alloc((size_t)NN * 768 * 2);
    float*    xg    = (float*)   alloc((size_t)3 * NN * 1024 * 4);
    float*    hnew3 = (float*)   alloc((size_t)3 * NN * DIM * 4);
    ushort_t* thead = (ushort_t*)alloc((size_t)NN * 512 * 2);
    float*    posb  = (float*)   alloc((size_t)NN * DIM * 4);

    const ushort_t* WqkvT = wtb + oWqkv;
    const ushort_t* bqkv  = wtb + obqkv;
    const ushort_t* WoT   = wtb + oWo;
    const ushort_t* bo    = wtb + obo;
    const ushort_t* ln1g  = wtb + oln1g;
    const ushort_t* ln1b  = wtb + oln1b;
    const ushort_t* ln2g  = wtb + oln2g;
    const ushort_t* ln2b  = wtb + oln2b;
    const ushort_t* W1T   = wtb + oW1;
    const ushort_t* b1    = wtb + ob1;
    const ushort_t* W2T   = wtb + oW2;
    const ushort_t* b2    = wtb + ob2;
    const ushort_t* type_emb = wtb + otype;
    const ushort_t* msgWT = wtb + omsgW;
    const ushort_t* msg_b = wtb + omsgb;
    const ushort_t* gatWT = wtb + ogatW;
    const ushort_t* gat_b = wtb + ogatb;
    const ushort_t* gasrc = wtb + oasrc;
    const ushort_t* gadst = wtb + oadst;
    const ushort_t* spW1T = wtb + ospW1;
    const ushort_t* spb1  = wtb + ospb1;
    const ushort_t* spW2T = wtb + ospW2;
    const ushort_t* spb2  = wtb + ospb2;
    const ushort_t* log_c = wtb + ologc;

    sniff_kernel<<<1, 256, 0, stream>>>((const unsigned int*)d_in[1], flag);
    convert_kernel<<<2048, 256, 0, stream>>>(ca, flag, wtb, wtotal);

    pe_kernel<<<SEQL, DIM, 0, stream>>>(pe);
    hipMemsetAsync(counts, 0, NN * 4, stream);
    hist_kernel<<<EDGES / 256, 256, 0, stream>>>(eidx, counts);
    scan_kernel<<<1, 256, 0, stream>>>(counts, indptr, cursor);
    scatter_kernel<<<EDGES / 256, 256, 0, stream>>>(eidx, etype, cursor, col_src, col_type);

    for (int c = 0; c < CHUNKS; ++c) {
        int row0 = c * CROWS;
        embed_kernel<<<CROWS, 64, 0, stream>>>(d_in[0], flag, tokens, pe, Xc, row0);
        for (int l = 0; l < 2; ++l) {
            gemm_bt<false, true><<<dim3(CROWS / 128, 6), 256, 0, stream>>>(
                Xc, WqkvT + (size_t)l * 196608, bqkv + l * 768, QKV, CROWS, 768, DIM, DIM, 0, 0);
            attn_mfma<<<dim3(CN, 4), 128, 0, stream>>>(QKV, Oc);
            gemm_ln<<<CROWS / 128, 512, 0, stream>>>(
                Oc, WoT + (size_t)l * 65536, bo + l * DIM, Xc, ln1g + l * DIM, ln1b + l * DIM, DIM);
            gemm_bt<true, true><<<dim3(CROWS / 128, 2), 256, 0, stream>>>(
                Xc, W1T + (size_t)l * 65536, b1 + l * DIM, Oc, CROWS, DIM, DIM, DIM, 0, 0);
            gemm_ln<<<CROWS / 128, 512, 0, stream>>>(
                Oc, W2T + (size_t)l * 65536, b2 + l * DIM, Xc, ln2g + l * DIM, ln2b + l * DIM, DIM);
        }
        mean_kernel<<<CN, DIM, 0, stream>>>(Xc, type_emb, rtypes, h, hb, c * CN);
    }

    for (int l = 0; l < 4; ++l) {
        gemm_bt<false, true><<<dim3(NN / 128, 6), 256, 0, stream>>>(
            hb, msgWT, msg_b, th, NN, 768, DIM, DIM, 0, 0);
        gemm_bt<false, false><<<dim3(NN / 128, 8, 3), 256, 0, stream>>>(
            th, gatWT + (size_t)l * 262144, nullptr, xg, NN, 1024, DIM, 768,
            (size_t)256, (size_t)NN * 1024);
        asad_kernel<<<dim3(NN, 3), 256, 0, stream>>>(xg, gasrc, gadst, a_s, a_d, l);
        edge_kernel<<<dim3(NN, 3), 256, 0, stream>>>(xg, a_s, a_d, indptr, col_src, col_type,
                                                     gat_b, hnew3, l);
        update_h_kernel<<<NN, 256, 0, stream>>>(h, hnew3, hb);
    }

    gemm_bt<true, true><<<dim3(NN / 128, 4), 256, 0, stream>>>(
        hb, spW1T, spb1, thead, NN, 512, DIM, DIM, 0, 0);
    gemm_bt<false, false><<<dim3(NN / 128, 2), 256, 0, stream>>>(
        thead, spW2T, spb2, posb, NN, DIM, 512, 512, 0, 0);
    final_kernel<<<NN, 64, 0, stream>>>(posb, log_c, flag, d_out);
}

// Round 6
// 1125.699 us; speedup vs baseline: 2.5257x; 1.0593x over previous
//
#include <hip/hip_runtime.h>
#include <hip/hip_bf16.h>

#define NN 2048
#define SEQL 64
#define DIM 256
#define NHEAD 8
#define EDGES 32768
#define CHUNKS 2
#define CN (NN / CHUNKS)          // 1024 nodes per chunk
#define CROWS (CN * SEQL)         // 65536 rows per chunk

typedef __attribute__((ext_vector_type(8))) short short8;
typedef __attribute__((ext_vector_type(4))) float f32x4;
typedef __attribute__((ext_vector_type(4))) unsigned short us4;
typedef unsigned short ushort_t;

__device__ __forceinline__ float us2f(unsigned short u) {
    union { unsigned int i; float f; } x; x.i = ((unsigned int)u) << 16; return x.f;
}
__device__ __forceinline__ unsigned short f2us(float f) {
    union { float f; unsigned int i; } u; u.f = f;
    unsigned int r = u.i + 0x7fffu + ((u.i >> 16) & 1u);
    return (unsigned short)(r >> 16);
}
__device__ __forceinline__ float lrelu02(float v) { return v < 0.f ? 0.2f * v : v; }

// async global->LDS, 16B per lane; LDS dest must be wave-uniform base
__device__ __forceinline__ void gload_lds16(const void* g, void* l) {
    __builtin_amdgcn_global_load_lds(
        (const __attribute__((address_space(1))) unsigned int*)g,
        (__attribute__((address_space(3))) unsigned int*)l, 16, 0, 0);
}

// ---------------------------------------------------------------------------
// dtype sniff (bf16-packed vs f32 inputs)
// ---------------------------------------------------------------------------
__global__ void sniff_kernel(const unsigned int* __restrict__ w, int* __restrict__ flag) {
    __shared__ int cnt;
    if (threadIdx.x == 0) cnt = 0;
    __syncthreads();
    unsigned int v = w[(size_t)threadIdx.x * 509];
    unsigned int e_lo = (v >> 7) & 0xffu;
    if (e_lo >= 0x6eu && e_lo <= 0x7fu) atomicAdd(&cnt, 1);
    __syncthreads();
    if (threadIdx.x == 0) *flag = (cnt > 128) ? 1 : 0;   // 1 = inputs are bf16
}

// ---------------------------------------------------------------------------
// Weight canonicalization to bf16, with optional per-slice transpose
// ---------------------------------------------------------------------------
#define NE 33
struct ConvArgs {
    const void* src[NE];
    unsigned int soff[NE];
    unsigned int off[NE + 1];
    unsigned int nel[NE];
    unsigned short ncol[NE];
    unsigned char klog2[NE];
};

__global__ void convert_kernel(ConvArgs a, const int* __restrict__ flag,
                               ushort_t* __restrict__ dst, unsigned int total) {
    const int bf = *flag;
    for (unsigned int i = blockIdx.x * 256 + threadIdx.x; i < total; i += gridDim.x * 256) {
        int e = 0;
        while (a.off[e + 1] <= i) ++e;
        unsigned int j = i - a.off[e];
        ushort_t v = 0;
        if (j < a.nel[e]) {
            unsigned int sidx;
            if (a.klog2[e]) {
                unsigned int K = 1u << a.klog2[e];
                unsigned int k = j & (K - 1), n = j >> a.klog2[e];
                sidx = k * (unsigned int)a.ncol[e] + n;
            } else sidx = j;
            sidx += a.soff[e];
            if (bf) v = ((const ushort_t*)a.src[e])[sidx];
            else    v = f2us(((const float*)a.src[e])[sidx]);
        }
        dst[i] = v;
    }
}

// ---------------------------------------------------------------------------
// bf16 MFMA GEMM, pre-transposed B, counted-vmcnt double-buffered pipeline,
// source-side chunk swizzle (conflict-free), bijective XCD block swizzle.
// C[z][.,N] = A[z][.,K] @ BT[N,K]^T (+bias)(+relu).  Requires gridX*gridY%8==0.
// ---------------------------------------------------------------------------
template <int K, bool RELU, bool OUT_BF16>
__global__ __launch_bounds__(256) void gemm_bt(
    const ushort_t* __restrict__ A, const ushort_t* __restrict__ BT,
    const ushort_t* __restrict__ bias, void* __restrict__ C,
    int N, int lda, size_t a_off_z, size_t c_off_z)
{
    __shared__ __align__(16) short a_lds[2][128][32];
    __shared__ __align__(16) short b_lds[2][128][32];

    const int tid  = threadIdx.x;
    const int lane = tid & 63;
    const int wave = tid >> 6;
    const int wr = wave >> 1, wc = wave & 1;

    // XCD-aware bijective swizzle: each XCD gets a contiguous m-major chunk
    const int gx = gridDim.x, gy = gridDim.y;
    const int nwg = gx * gy;
    const int lin = blockIdx.y * gx + blockIdx.x;
    const int q8 = nwg >> 3;
    const int sid = (lin & 7) * q8 + (lin >> 3);
    const int mb = sid / gy;
    const int nb = sid - mb * gy;
    const size_t mbase = (size_t)mb * 128;
    const size_t nbase = (size_t)nb * 128;

    A += (size_t)blockIdx.z * a_off_z;
    const size_t czoff = (size_t)blockIdx.z * c_off_z;

    f32x4 acc[4][4];
    const f32x4 fzero = {0.f, 0.f, 0.f, 0.f};
#pragma unroll
    for (int i = 0; i < 4; ++i)
#pragma unroll
        for (int j = 0; j < 4; ++j) acc[i][j] = fzero;

    const int srow = tid >> 2;          // 0..63
    const int ksw0 = (((tid & 3) ^ ((srow >> 1) & 3)) * 8);   // swizzled chunk
    const int rl = lane & 15;
    const int kfs = (((lane >> 4) ^ ((rl >> 1) & 3)) * 8);

    constexpr int nk = K >> 5;
    auto stage = [&](int buf, int k0) {
        short* lA = &a_lds[buf][0][0] + wave * 512;
        short* lB = &b_lds[buf][0][0] + wave * 512;
        gload_lds16(A  + (mbase + srow)      * (size_t)lda + k0 + ksw0, lA);
        gload_lds16(A  + (mbase + srow + 64) * (size_t)lda + k0 + ksw0, lA + 2048);
        gload_lds16(BT + (nbase + srow)      * (size_t)K   + k0 + ksw0, lB);
        gload_lds16(BT + (nbase + srow + 64) * (size_t)K   + k0 + ksw0, lB + 2048);
    };

    stage(0, 0);
    if (nk > 1) stage(1, 32);
#pragma unroll
    for (int t = 0; t < nk; ++t) {
        const int cur = t & 1;
        if (t + 1 < nk) { asm volatile("s_waitcnt vmcnt(4)" ::: "memory"); }
        else            { asm volatile("s_waitcnt vmcnt(0)" ::: "memory"); }
        __builtin_amdgcn_s_barrier();
        __builtin_amdgcn_sched_barrier(0);

        short8 af[4], bfr[4];
#pragma unroll
        for (int m = 0; m < 4; ++m) af[m]  = *(const short8*)&a_lds[cur][wr * 64 + m * 16 + rl][kfs];
#pragma unroll
        for (int n = 0; n < 4; ++n) bfr[n] = *(const short8*)&b_lds[cur][wc * 64 + n * 16 + rl][kfs];
        asm volatile("s_waitcnt lgkmcnt(0)" ::: "memory");
        __builtin_amdgcn_sched_barrier(0);
#pragma unroll
        for (int m = 0; m < 4; ++m)
#pragma unroll
            for (int n = 0; n < 4; ++n)
                acc[m][n] = __builtin_amdgcn_mfma_f32_16x16x32_bf16(af[m], bfr[n], acc[m][n], 0, 0, 0);
        __builtin_amdgcn_s_barrier();
        __builtin_amdgcn_sched_barrier(0);
        if (t + 2 < nk) stage(cur, (t + 2) * 32);
    }

    const int rq = (lane >> 4) * 4;
#pragma unroll
    for (int m = 0; m < 4; ++m) {
#pragma unroll
        for (int n = 0; n < 4; ++n) {
            size_t gcol = nbase + wc * 64 + n * 16 + rl;
            float bv = bias ? us2f(bias[gcol]) : 0.f;
#pragma unroll
            for (int p = 0; p < 4; ++p) {
                size_t grow = mbase + wr * 64 + m * 16 + rq + p;
                float v = acc[m][n][p] + bv;
                if (RELU) v = fmaxf(v, 0.f);
                if (OUT_BF16) ((ushort_t*)C)[czoff + grow * N + gcol] = f2us(v);
                else          ((float*)C)[czoff + grow * N + gcol] = v;
            }
        }
    }
}

// ---------------------------------------------------------------------------
// Fused GEMM + residual + LayerNorm (N=256): X = LN(X + A@BT^T + bias)*g + b
// tile 128x256, 512 threads (8 waves 2x4), counted-vmcnt dbuf pipeline
// ---------------------------------------------------------------------------
template <int K>
__global__ __launch_bounds__(512) void gemm_ln(
    const ushort_t* __restrict__ A, const ushort_t* __restrict__ BT,
    const ushort_t* __restrict__ bias, ushort_t* __restrict__ X,
    const ushort_t* __restrict__ gg, const ushort_t* __restrict__ bb)
{
    __shared__ __align__(16) short a_lds[2][128][32];
    __shared__ __align__(16) short b_lds[2][256][32];
    __shared__ float st_part[128][8];
    __shared__ float st_fin[128][2];

    const int tid  = threadIdx.x;
    const int lane = tid & 63;
    const int wave = tid >> 6;
    const int wr = wave >> 2, wc = wave & 3;
    const size_t mbase = (size_t)blockIdx.x * 128;

    f32x4 acc[4][4];
    const f32x4 fzero = {0.f, 0.f, 0.f, 0.f};
#pragma unroll
    for (int i = 0; i < 4; ++i)
#pragma unroll
        for (int j = 0; j < 4; ++j) acc[i][j] = fzero;

    const int srow = tid >> 2;          // 0..127
    const int ksw0 = (((tid & 3) ^ ((srow >> 1) & 3)) * 8);
    const int rl = lane & 15;
    const int g  = lane >> 4;
    const int kfs = ((g ^ ((rl >> 1) & 3)) * 8);

    constexpr int nk = K >> 5;
    auto stage = [&](int buf, int k0) {
        gload_lds16(A  + (mbase + srow) * (size_t)K + k0 + ksw0,
                    &a_lds[buf][0][0] + wave * 512);
        gload_lds16(BT + (size_t)srow         * K + k0 + ksw0,
                    &b_lds[buf][0][0] + wave * 512);
        gload_lds16(BT + (size_t)(srow + 128) * K + k0 + ksw0,
                    &b_lds[buf][0][0] + wave * 512 + 4096);
    };

    stage(0, 0);
    if (nk > 1) stage(1, 32);
#pragma unroll
    for (int t = 0; t < nk; ++t) {
        const int cur = t & 1;
        if (t + 1 < nk) { asm volatile("s_waitcnt vmcnt(3)" ::: "memory"); }
        else            { asm volatile("s_waitcnt vmcnt(0)" ::: "memory"); }
        __builtin_amdgcn_s_barrier();
        __builtin_amdgcn_sched_barrier(0);

        short8 af[4], bfr[4];
#pragma unroll
        for (int m = 0; m < 4; ++m) af[m]  = *(const short8*)&a_lds[cur][wr * 64 + m * 16 + rl][kfs];
#pragma unroll
        for (int n = 0; n < 4; ++n) bfr[n] = *(const short8*)&b_lds[cur][wc * 64 + n * 16 + rl][kfs];
        asm volatile("s_waitcnt lgkmcnt(0)" ::: "memory");
        __builtin_amdgcn_sched_barrier(0);
#pragma unroll
        for (int m = 0; m < 4; ++m)
#pragma unroll
            for (int n = 0; n < 4; ++n)
                acc[m][n] = __builtin_amdgcn_mfma_f32_16x16x32_bf16(af[m], bfr[n], acc[m][n], 0, 0, 0);
        __builtin_amdgcn_s_barrier();
        __builtin_amdgcn_sched_barrier(0);
        if (t + 2 < nk) stage(cur, (t + 2) * 32);
    }

#pragma unroll
    for (int m = 0; m < 4; ++m)
#pragma unroll
        for (int n = 0; n < 4; ++n) {
            int gcol = wc * 64 + n * 16 + rl;
            float bv = us2f(bias[gcol]);
#pragma unroll
            for (int r = 0; r < 4; ++r) {
                size_t grow = mbase + wr * 64 + m * 16 + g * 4 + r;
                acc[m][n][r] += bv + us2f(X[grow * 256 + gcol]);
            }
        }
#pragma unroll
    for (int m = 0; m < 4; ++m)
#pragma unroll
        for (int r = 0; r < 4; ++r) {
            float ps = 0.f, pq = 0.f;
#pragma unroll
            for (int n = 0; n < 4; ++n) { float v = acc[m][n][r]; ps += v; pq += v * v; }
#pragma unroll
            for (int off = 1; off < 16; off <<= 1) { ps += __shfl_xor(ps, off); pq += __shfl_xor(pq, off); }
            if (rl == 0) {
                int row = wr * 64 + m * 16 + g * 4 + r;
                st_part[row][wc] = ps;
                st_part[row][4 + wc] = pq;
            }
        }
    __syncthreads();
    if (tid < 128) {
        float s = st_part[tid][0] + st_part[tid][1] + st_part[tid][2] + st_part[tid][3];
        float q = st_part[tid][4] + st_part[tid][5] + st_part[tid][6] + st_part[tid][7];
        float mean = s * (1.f / 256.f);
        float var = q * (1.f / 256.f) - mean * mean;
        st_fin[tid][0] = mean;
        st_fin[tid][1] = rsqrtf(var + 1e-5f);
    }
    __syncthreads();
#pragma unroll
    for (int m = 0; m < 4; ++m)
#pragma unroll
        for (int n = 0; n < 4; ++n) {
            int gcol = wc * 64 + n * 16 + rl;
            float gv = us2f(gg[gcol]), bv = us2f(bb[gcol]);
#pragma unroll
            for (int r = 0; r < 4; ++r) {
                int row = wr * 64 + m * 16 + g * 4 + r;
                float out = (acc[m][n][r] - st_fin[row][0]) * st_fin[row][1] * gv + bv;
                X[(mbase + row) * 256 + gcol] = f2us(out);
            }
        }
}

// ---------------------------------------------------------------------------
// MFMA attention: 1 wave per (node, head); 2 waves per block.
// ---------------------------------------------------------------------------
__global__ __launch_bounds__(128) void attn_mfma(const ushort_t* __restrict__ qkv,
                                                 ushort_t* __restrict__ O) {
    __shared__ ushort_t smem[2][6912];
    const int w = threadIdx.x >> 6, lane = threadIdx.x & 63;
    const int h = blockIdx.y * 2 + w;
    const int rl = lane & 15, g = lane >> 4;
    const size_t rowbase = (size_t)blockIdx.x * 64;
    ushort_t* vt = smem[w];
    ushort_t* pl = smem[w] + 2304;

    const ushort_t* vp = qkv + (rowbase + lane) * 768 + 512 + h * 32;
#pragma unroll
    for (int i = 0; i < 4; ++i) {
        union { short8 v; ushort_t s[8]; } u;
        u.v = *(const short8*)(vp + i * 8);
#pragma unroll
        for (int j = 0; j < 8; ++j) vt[(i * 8 + j) * 72 + lane] = u.s[j];
    }

    short8 kf[4], qf[4];
#pragma unroll
    for (int t = 0; t < 4; ++t) {
        kf[t] = *(const short8*)(qkv + (rowbase + t * 16 + rl) * 768 + 256 + h * 32 + g * 8);
        qf[t] = *(const short8*)(qkv + (rowbase + t * 16 + rl) * 768 +       h * 32 + g * 8);
    }

    f32x4 s[4][4];
    const f32x4 fzero = {0.f, 0.f, 0.f, 0.f};
#pragma unroll
    for (int kt = 0; kt < 4; ++kt)
#pragma unroll
        for (int qt = 0; qt < 4; ++qt) s[kt][qt] = fzero;
#pragma unroll
    for (int kt = 0; kt < 4; ++kt)
#pragma unroll
        for (int qt = 0; qt < 4; ++qt)
            s[kt][qt] = __builtin_amdgcn_mfma_f32_16x16x32_bf16(kf[kt], qf[qt], s[kt][qt], 0, 0, 0);

    const float sc = 0.17677669529663687f;
    float inv[4];
#pragma unroll
    for (int qt = 0; qt < 4; ++qt) {
        float m = -1e30f;
#pragma unroll
        for (int kt = 0; kt < 4; ++kt)
#pragma unroll
            for (int r = 0; r < 4; ++r) { s[kt][qt][r] *= sc; m = fmaxf(m, s[kt][qt][r]); }
        m = fmaxf(m, __shfl_xor(m, 16));
        m = fmaxf(m, __shfl_xor(m, 32));
        float sum = 0.f;
#pragma unroll
        for (int kt = 0; kt < 4; ++kt)
#pragma unroll
            for (int r = 0; r < 4; ++r) { float e = __expf(s[kt][qt][r] - m); s[kt][qt][r] = e; sum += e; }
        sum += __shfl_xor(sum, 16);
        sum += __shfl_xor(sum, 32);
        inv[qt] = 1.f / sum;
    }

#pragma unroll
    for (int qt = 0; qt < 4; ++qt)
#pragma unroll
        for (int kt = 0; kt < 4; ++kt) {
            us4 pk;
#pragma unroll
            for (int r = 0; r < 4; ++r) pk[r] = f2us(s[kt][qt][r] * inv[qt]);
            *(us4*)&pl[(qt * 16 + rl) * 72 + kt * 16 + g * 4] = pk;
        }
    asm volatile("s_waitcnt lgkmcnt(0)" ::: "memory");
    __builtin_amdgcn_sched_barrier(0);

    f32x4 o[2][4];
#pragma unroll
    for (int dt = 0; dt < 2; ++dt)
#pragma unroll
        for (int qt = 0; qt < 4; ++qt) o[dt][qt] = fzero;
#pragma unroll
    for (int ks = 0; ks < 2; ++ks) {
        short8 va[2];
#pragma unroll
        for (int dt = 0; dt < 2; ++dt)
            va[dt] = *(const short8*)&vt[(dt * 16 + rl) * 72 + ks * 32 + g * 8];
#pragma unroll
        for (int qt = 0; qt < 4; ++qt) {
            short8 pb = *(const short8*)&pl[(qt * 16 + rl) * 72 + ks * 32 + g * 8];
#pragma unroll
            for (int dt = 0; dt < 2; ++dt)
                o[dt][qt] = __builtin_amdgcn_mfma_f32_16x16x32_bf16(va[dt], pb, o[dt][qt], 0, 0, 0);
        }
    }

#pragma unroll
    for (int dt = 0; dt < 2; ++dt)
#pragma unroll
        for (int qt = 0; qt < 4; ++qt) {
            us4 ov;
#pragma unroll
            for (int r = 0; r < 4; ++r) ov[r] = f2us(o[dt][qt][r]);
            *(us4*)&pl[(qt * 16 + rl) * 40 + dt * 16 + g * 4] = ov;
        }
    asm volatile("s_waitcnt lgkmcnt(0)" ::: "memory");
    __builtin_amdgcn_sched_barrier(0);
    ushort_t* op = O + (rowbase + lane) * 256 + h * 32;
#pragma unroll
    for (int t = 0; t < 4; ++t)
        *(short8*)(op + t * 8) = *(const short8*)&pl[lane * 40 + t * 8];
}

// ---------------------------------------------------------------------------
__global__ void pe_kernel(float* __restrict__ pe) {
    int s = blockIdx.x, d = threadIdx.x;
    int i = d >> 1;
    float freq = __expf((float)(2 * i) * (-9.210340371976184f / 256.f));
    float ang = (float)s * freq;
    pe[s * DIM + d] = (d & 1) ? cosf(ang) : sinf(ang);
}

// vectorized x4: 64 threads per row
__global__ __launch_bounds__(64) void embed_kernel(const void* __restrict__ tok_emb,
                                                   const int* __restrict__ flag,
                                                   const int* __restrict__ tokens,
                                                   const float* __restrict__ pe,
                                                   ushort_t* __restrict__ X, int row0) {
    int lr = blockIdx.x, t = threadIdx.x;
    int grow = row0 + lr;
    int tok = tokens[grow];
    int s = grow & 63;
    int d0 = t * 4;
    size_t idx = (size_t)tok * DIM + d0;
    f32x4 pv = *(const f32x4*)&pe[s * DIM + d0];
    us4 out;
    if (*flag) {
        us4 tv = *(const us4*)((const ushort_t*)tok_emb + idx);
#pragma unroll
        for (int j = 0; j < 4; ++j) out[j] = f2us(us2f(tv[j]) * 16.f + pv[j]);
    } else {
        f32x4 tv = *(const f32x4*)((const float*)tok_emb + idx);
#pragma unroll
        for (int j = 0; j < 4; ++j) out[j] = f2us(tv[j] * 16.f + pv[j]);
    }
    *(us4*)&X[(size_t)lr * DIM + d0] = out;
}

__global__ void mean_kernel(const ushort_t* __restrict__ Xc,
                            const ushort_t* __restrict__ type_emb,
                            const int* __restrict__ rtypes,
                            float* __restrict__ h, ushort_t* __restrict__ hb, int n0) {
    int nl = blockIdx.x, d = threadIdx.x;
    float acc = 0.f;
    for (int s = 0; s < 64; ++s) acc += us2f(Xc[((size_t)nl * 64 + s) * DIM + d]);
    int n = n0 + nl;
    float val = acc * (1.f / 64.f) + us2f(type_emb[(size_t)rtypes[n] * DIM + d]);
    h[(size_t)n * DIM + d] = val;
    hb[(size_t)n * DIM + d] = f2us(val);
}

// ---------------------------------------------------------------------------
// CSR build (by dst)
// ---------------------------------------------------------------------------
__global__ void hist_kernel(const int* __restrict__ ei, int* __restrict__ counts) {
    int e = blockIdx.x * 256 + threadIdx.x;
    if (e < EDGES) atomicAdd(&counts[ei[EDGES + e]], 1);
}
__global__ __launch_bounds__(256) void scan_kernel(const int* __restrict__ counts,
                                                   int* __restrict__ indptr,
                                                   int* __restrict__ cursor) {
    __shared__ int part[256];
    int t = threadIdx.x;
    int local[8]; int s = 0;
#pragma unroll
    for (int i = 0; i < 8; ++i) { local[i] = s; s += counts[t * 8 + i]; }
    part[t] = s;
    __syncthreads();
    for (int d = 1; d < 256; d <<= 1) {
        int val = (t >= d) ? part[t - d] : 0;
        __syncthreads();
        part[t] += val;
        __syncthreads();
    }
    int base = part[t] - s;
#pragma unroll
    for (int i = 0; i < 8; ++i) { int v = base + local[i]; indptr[t * 8 + i] = v; cursor[t * 8 + i] = v; }
    if (t == 255) indptr[NN] = part[255];
}
__global__ void scatter_kernel(const int* __restrict__ ei, const int* __restrict__ et,
                               int* __restrict__ cursor, int* __restrict__ col_src,
                               int* __restrict__ col_type) {
    int e = blockIdx.x * 256 + threadIdx.x;
    if (e < EDGES) {
        int d = ei[EDGES + e];
        int pp = atomicAdd(&cursor[d], 1);
        col_src[pp] = ei[e];
        col_type[pp] = et[e];
    }
}

// a_s/a_d: grid (NN, 3), block 256 = 4 head-waves
__global__ __launch_bounds__(256) void asad_kernel(const float* __restrict__ xg,
                                                   const ushort_t* __restrict__ asrc,
                                                   const ushort_t* __restrict__ adst,
                                                   float* __restrict__ a_s, float* __restrict__ a_d,
                                                   int l) {
    int n = blockIdx.x, r = blockIdx.y, g = threadIdx.x >> 6, lane = threadIdx.x & 63;
    const float* xp = xg + ((size_t)r * NN + n) * 1024 + g * 256 + lane * 4;
    const ushort_t* sp = asrc + ((size_t)l * 4 + g) * 256 + lane * 4;
    const ushort_t* dp = adst + ((size_t)l * 4 + g) * 256 + lane * 4;
    float ss = 0.f, dd = 0.f;
#pragma unroll
    for (int j = 0; j < 4; ++j) { float x = xp[j]; ss += x * us2f(sp[j]); dd += x * us2f(dp[j]); }
#pragma unroll
    for (int off = 32; off > 0; off >>= 1) { ss += __shfl_xor(ss, off); dd += __shfl_xor(dd, off); }
    if (lane == 0) {
        a_s[((size_t)r * NN + n) * 4 + g] = ss;
        a_d[((size_t)r * NN + n) * 4 + g] = dd;
    }
}

// GAT edge-softmax + aggregate: grid (NN, 3); writes hnew3[r] (no memset)
__global__ __launch_bounds__(256) void edge_kernel(const float* __restrict__ xg,
                                                   const float* __restrict__ a_s,
                                                   const float* __restrict__ a_d,
                                                   const int* __restrict__ indptr,
                                                   const int* __restrict__ col_src,
                                                   const int* __restrict__ col_type,
                                                   const ushort_t* __restrict__ gat_b,
                                                   float* __restrict__ hnew3, int l) {
    __shared__ float outs[4][256];
    int n = blockIdx.x, r = blockIdx.y, g = threadIdx.x >> 6, lane = threadIdx.x & 63;
    int beg = indptr[n], end = indptr[n + 1];
    const size_t rb = (size_t)r * NN;
    float adn = a_d[(rb + n) * 4 + g];
    float eself = lrelu02(a_s[(rb + n) * 4 + g] + adn);
    float m = eself;
    for (int e = beg; e < end; ++e) {
        if (col_type[e] == r) {
            float v = lrelu02(a_s[(rb + col_src[e]) * 4 + g] + adn);
            m = fmaxf(m, v);
        }
    }
    float wself = __expf(eself - m);
    float denom = wself;
    const float* xn = xg + (rb + n) * 1024 + g * 256 + lane * 4;
    float num[4];
#pragma unroll
    for (int j = 0; j < 4; ++j) num[j] = wself * xn[j];
    for (int e = beg; e < end; ++e) {
        if (col_type[e] == r) {
            int src = col_src[e];
            float v = lrelu02(a_s[(rb + src) * 4 + g] + adn);
            float w = __expf(v - m);
            denom += w;
            const float* xs = xg + (rb + src) * 1024 + g * 256 + lane * 4;
#pragma unroll
            for (int j = 0; j < 4; ++j) num[j] += w * xs[j];
        }
    }
    float invd = 1.f / denom;
#pragma unroll
    for (int j = 0; j < 4; ++j) outs[g][lane * 4 + j] = num[j] * invd;
    __syncthreads();
    int d = threadIdx.x;
    float hv = 0.25f * (outs[0][d] + outs[1][d] + outs[2][d] + outs[3][d]) + us2f(gat_b[l * 256 + d]);
    hnew3[(rb + n) * 256 + d] = hv;
}

__global__ void update_h_kernel(float* __restrict__ h, const float* __restrict__ hnew3,
                                ushort_t* __restrict__ hb) {
    size_t i = (size_t)blockIdx.x * 256 + threadIdx.x;
    float v = fmaxf(h[i] + hnew3[i] + hnew3[(size_t)NN * 256 + i] + hnew3[(size_t)2 * NN * 256 + i], 0.f);
    h[i] = v;
    hb[i] = f2us(v);
}

__global__ __launch_bounds__(64) void final_kernel(const float* __restrict__ pos,
                                                   const ushort_t* __restrict__ log_c,
                                                   const int* __restrict__ flag,
                                                   void* __restrict__ out) {
    int n = blockIdx.x, lane = threadIdx.x;
    int bf = *flag;
    float scv = sqrtf(__expf(us2f(log_c[0])));
    f32x4 pv = *(const f32x4*)&pos[(size_t)n * 256 + lane * 4];
    float st[4]; float sq = 0.f;
#pragma unroll
    for (int j = 0; j < 4; ++j) { float t = tanhf(pv[j]) * 2.f * scv; st[j] = t; sq += t * t; }
#pragma unroll
    for (int off = 32; off > 0; off >>= 1) sq += __shfl_xor(sq, off);
    float rr = fmaxf(sqrtf(sq), 1e-8f);
    float sf = sinhf(rr) / rr;
    if (bf) {
        ushort_t* o = (ushort_t*)out;
        if (lane == 0) o[(size_t)n * 257] = f2us(coshf(rr));
#pragma unroll
        for (int j = 0; j < 4; ++j) o[(size_t)n * 257 + 1 + lane * 4 + j] = f2us(sf * st[j]);
    } else {
        float* o = (float*)out;
        if (lane == 0) o[(size_t)n * 257] = coshf(rr);
#pragma unroll
        for (int j = 0; j < 4; ++j) o[(size_t)n * 257 + 1 + lane * 4 + j] = sf * st[j];
    }
}

// ---------------------------------------------------------------------------
extern "C" void kernel_launch(void* const* d_in, const int* in_sizes, int n_in,
                              void* d_out, int out_size, void* d_ws, size_t ws_size,
                              hipStream_t stream) {
    const int* tokens = (const int*)d_in[25];
    const int* rtypes = (const int*)d_in[26];
    const int* eidx   = (const int*)d_in[27];
    const int* etype  = (const int*)d_in[28];

    char* base = (char*)d_ws;
    size_t pos = 0;
    auto alloc = [&](size_t b) -> char* {
        char* r = base + pos; pos = (pos + b + 255) & ~(size_t)255; return r;
    };

    int* flag = (int*)alloc(256);

    // ---- conversion table (weights -> canonical bf16, B^T for GEMMs)
    ConvArgs ca;
    int ne = 0; unsigned int off = 0;
    auto add = [&](const void* src, unsigned int soff, unsigned int elems,
                   int klog2, int ncol) -> unsigned int {
        ca.src[ne] = src; ca.soff[ne] = soff; ca.off[ne] = off;
        ca.nel[ne] = elems; ca.klog2[ne] = (unsigned char)klog2;
        ca.ncol[ne] = (unsigned short)ncol;
        unsigned int r = off; off += (elems + 7) & ~7u; ++ne; return r;
    };
    unsigned int oWqkv = add(d_in[1], 0, 196608, 8, 768);
                         add(d_in[1], 196608, 196608, 8, 768);
    unsigned int obqkv = add(d_in[2], 0, 1536, 0, 0);
    unsigned int oWo   = add(d_in[3], 0, 65536, 8, 256);
                         add(d_in[3], 65536, 65536, 8, 256);
    unsigned int obo   = add(d_in[4], 0, 512, 0, 0);
    unsigned int oln1g = add(d_in[5], 0, 512, 0, 0);
    unsigned int oln1b = add(d_in[6], 0, 512, 0, 0);
    unsigned int oln2g = add(d_in[7], 0, 512, 0, 0);
    unsigned int oln2b = add(d_in[8], 0, 512, 0, 0);
    unsigned int oW1   = add(d_in[9], 0, 65536, 8, 256);
                         add(d_in[9], 65536, 65536, 8, 256);
    unsigned int ob1   = add(d_in[10], 0, 512, 0, 0);
    unsigned int oW2   = add(d_in[11], 0, 65536, 8, 256);
                         add(d_in[11], 65536, 65536, 8, 256);
    unsigned int ob2   = add(d_in[12], 0, 512, 0, 0);
    unsigned int otype = add(d_in[13], 0, 2560, 0, 0);
    unsigned int omsgW = add(d_in[14], 0, 65536, 8, 256);
                         add(d_in[14], 65536, 65536, 8, 256);
                         add(d_in[14], 131072, 65536, 8, 256);
    unsigned int omsgb = add(d_in[15], 0, 768, 0, 0);
    unsigned int ogatW = add(d_in[16], 0, 262144, 8, 1024);
                         add(d_in[16], 262144, 262144, 8, 1024);
                         add(d_in[16], 524288, 262144, 8, 1024);
                         add(d_in[16], 786432, 262144, 8, 1024);
    unsigned int ogatb = add(d_in[17], 0, 1024, 0, 0);
    unsigned int oasrc = add(d_in[18], 0, 4096, 0, 0);
    unsigned int oadst = add(d_in[19], 0, 4096, 0, 0);
    unsigned int ospW1 = add(d_in[20], 0, 131072, 8, 512);
    unsigned int ospb1 = add(d_in[21], 0, 512, 0, 0);
    unsigned int ospW2 = add(d_in[22], 0, 131072, 9, 256);
    unsigned int ospb2 = add(d_in[23], 0, 256, 0, 0);
    unsigned int ologc = add(d_in[24], 0, 1, 0, 0);
    ca.off[ne] = off;
    unsigned int wtotal = off;

    // persistent allocations
    ushort_t* wtb   = (ushort_t*)alloc((size_t)wtotal * 2);
    float*    pe    = (float*)   alloc((size_t)SEQL * DIM * 4);
    float*    h     = (float*)   alloc((size_t)NN * DIM * 4);
    ushort_t* hb    = (ushort_t*)alloc((size_t)NN * DIM * 2);
    float*    a_s   = (float*)   alloc((size_t)3 * NN * 4 * 4);
    float*    a_d   = (float*)   alloc((size_t)3 * NN * 4 * 4);
    int*      counts = (int*)    alloc((size_t)NN * 4);
    int*      indptr = (int*)    alloc((size_t)(NN + 1) * 4);
    int*      cursor = (int*)    alloc((size_t)NN * 4);
    int*      col_src  = (int*)  alloc((size_t)EDGES * 4);
    int*      col_type = (int*)  alloc((size_t)EDGES * 4);

    // phase-shared scratch
    size_t spos0 = pos;
    ushort_t* Xc  = (ushort_t*)alloc((size_t)CROWS * DIM * 2);   // 32 MB
    ushort_t* QKV = (ushort_t*)alloc((size_t)CROWS * 768 * 2);   // 96 MB
    ushort_t* Oc  = (ushort_t*)alloc((size_t)CROWS * DIM * 2);   // 32 MB
    pos = spos0;                                                  // overlap phase 2
    ushort_t* th    = (ushort_t*)alloc((size_t)NN * 768 * 2);
    float*    xg    = (float*)   alloc((size_t)3 * NN * 1024 * 4);
    float*    hnew3 = (float*)   alloc((size_t)3 * NN * DIM * 4);
    ushort_t* thead = (ushort_t*)alloc((size_t)NN * 512 * 2);
    float*    posb  = (float*)   alloc((size_t)NN * DIM * 4);

    const ushort_t* WqkvT = wtb + oWqkv;
    const ushort_t* bqkv  = wtb + obqkv;
    const ushort_t* WoT   = wtb + oWo;
    const ushort_t* bo    = wtb + obo;
    const ushort_t* ln1g  = wtb + oln1g;
    const ushort_t* ln1b  = wtb + oln1b;
    const ushort_t* ln2g  = wtb + oln2g;
    const ushort_t* ln2b  = wtb + oln2b;
    const ushort_t* W1T   = wtb + oW1;
    const ushort_t* b1    = wtb + ob1;
    const ushort_t* W2T   = wtb + oW2;
    const ushort_t* b2    = wtb + ob2;
    const ushort_t* type_emb = wtb + otype;
    const ushort_t* msgWT = wtb + omsgW;
    const ushort_t* msg_b = wtb + omsgb;
    const ushort_t* gatWT = wtb + ogatW;
    const ushort_t* gat_b = wtb + ogatb;
    const ushort_t* gasrc = wtb + oasrc;
    const ushort_t* gadst = wtb + oadst;
    const ushort_t* spW1T = wtb + ospW1;
    const ushort_t* spb1  = wtb + ospb1;
    const ushort_t* spW2T = wtb + ospW2;
    const ushort_t* spb2  = wtb + ospb2;
    const ushort_t* log_c = wtb + ologc;

    sniff_kernel<<<1, 256, 0, stream>>>((const unsigned int*)d_in[1], flag);
    convert_kernel<<<2048, 256, 0, stream>>>(ca, flag, wtb, wtotal);

    pe_kernel<<<SEQL, DIM, 0, stream>>>(pe);
    hipMemsetAsync(counts, 0, NN * 4, stream);
    hist_kernel<<<EDGES / 256, 256, 0, stream>>>(eidx, counts);
    scan_kernel<<<1, 256, 0, stream>>>(counts, indptr, cursor);
    scatter_kernel<<<EDGES / 256, 256, 0, stream>>>(eidx, etype, cursor, col_src, col_type);

    for (int c = 0; c < CHUNKS; ++c) {
        int row0 = c * CROWS;
        embed_kernel<<<CROWS, 64, 0, stream>>>(d_in[0], flag, tokens, pe, Xc, row0);
        for (int l = 0; l < 2; ++l) {
            gemm_bt<256, false, true><<<dim3(CROWS / 128, 6), 256, 0, stream>>>(
                Xc, WqkvT + (size_t)l * 196608, bqkv + l * 768, QKV, 768, DIM, 0, 0);
            attn_mfma<<<dim3(CN, 4), 128, 0, stream>>>(QKV, Oc);
            gemm_ln<256><<<CROWS / 128, 512, 0, stream>>>(
                Oc, WoT + (size_t)l * 65536, bo + l * DIM, Xc, ln1g + l * DIM, ln1b + l * DIM);
            gemm_bt<256, true, true><<<dim3(CROWS / 128, 2), 256, 0, stream>>>(
                Xc, W1T + (size_t)l * 65536, b1 + l * DIM, Oc, DIM, DIM, 0, 0);
            gemm_ln<256><<<CROWS / 128, 512, 0, stream>>>(
                Oc, W2T + (size_t)l * 65536, b2 + l * DIM, Xc, ln2g + l * DIM, ln2b + l * DIM);
        }
        mean_kernel<<<CN, DIM, 0, stream>>>(Xc, type_emb, rtypes, h, hb, c * CN);
    }

    for (int l = 0; l < 4; ++l) {
        gemm_bt<256, false, true><<<dim3(NN / 128, 6), 256, 0, stream>>>(
            hb, msgWT, msg_b, th, 768, DIM, 0, 0);
        gemm_bt<256, false, false><<<dim3(NN / 128, 8, 3), 256, 0, stream>>>(
            th, gatWT + (size_t)l * 262144, nullptr, xg, 1024, 768,
            (size_t)256, (size_t)NN * 1024);
        asad_kernel<<<dim3(NN, 3), 256, 0, stream>>>(xg, gasrc, gadst, a_s, a_d, l);
        edge_kernel<<<dim3(NN, 3), 256, 0, stream>>>(xg, a_s, a_d, indptr, col_src, col_type,
                                                     gat_b, hnew3, l);
        update_h_kernel<<<NN, 256, 0, stream>>>(h, hnew3, hb);
    }

    gemm_bt<256, true, true><<<dim3(NN / 128, 4), 256, 0, stream>>>(
        hb, spW1T, spb1, thead, 512, DIM, 0, 0);
    gemm_bt<512, false, false><<<dim3(NN / 128, 2), 256, 0, stream>>>(
        thead, spW2T, spb2, posb, DIM, 512, 0, 0);
    final_kernel<<<NN, 64, 0, stream>>>(posb, log_c, flag, d_out);
}